// Round 6
// baseline (6896.694 us; speedup 1.0000x reference)
//
#include <hip/hip_runtime.h>

#define B_ 256
#define S_ 128
#define F_ 512
#define H_ 1024
#define A_ 18
#define M_ (B_*S_)      // 32768 output rows (b*S+s)
#define G_ (4*H_)       // 4096 gate cols, permuted unit-major: p = unit*4 + {i,f,g,o}
#define CH_ 8           // timesteps per chunk
#define CR_ (B_*CH_)    // 2048 rows per chunk, row rg = b*CH_ + dt

typedef unsigned short u16;
typedef __attribute__((ext_vector_type(8))) _Float16 f16x8;  // 8 fp16 = 4 VGPR
typedef __attribute__((ext_vector_type(8))) short   s16x8;
typedef __attribute__((ext_vector_type(4))) float f32x4;

__device__ __forceinline__ float bf2f(u16 u){
  union{unsigned int i; float f;} v; v.i=((unsigned int)u)<<16; return v.f;
}
__device__ __forceinline__ u16 f2bf(float f){
  unsigned int i=__float_as_uint(f);
  unsigned int r=(i+0x7fffu+((i>>16)&1u))>>16;   // RNE
  return (u16)r;
}
__device__ __forceinline__ u16 f2h(float f){
  _Float16 h=(_Float16)f;
  union{_Float16 h; u16 u;} v; v.h=h; return v.u;
}
// mode-aware scalar load of logical float element i (1: fp32, 0: bf16)
__device__ __forceinline__ float ldf(const void* p, size_t i, int m){
  return m ? ((const float*)p)[i] : bf2f(((const u16*)p)[i]);
}
// load 8 logical floats -> fp16x8. mode 0: bf16 src, 1: fp32 src, 2: raw fp16 src.
__device__ __forceinline__ f16x8 load8_h(const void* base, size_t off, int m){
  f16x8 v;
  if(m==2) return *(const f16x8*)((const u16*)base + off);
  if(m==1){
    const float* f=(const float*)base + off;
    float4 a=*(const float4*)f; float4 b=*(const float4*)(f+4);
    v[0]=(_Float16)a.x; v[1]=(_Float16)a.y; v[2]=(_Float16)a.z; v[3]=(_Float16)a.w;
    v[4]=(_Float16)b.x; v[5]=(_Float16)b.y; v[6]=(_Float16)b.z; v[7]=(_Float16)b.w;
    return v;
  }
  s16x8 w=*(const s16x8*)((const u16*)base + off);
#pragma unroll
  for(int k=0;k<8;k++) v[k]=(_Float16)bf2f((u16)w[k]);
  return v;
}

// ---- Stage ROWS x 64 fp16 tile into LDS [ROWS][64], XOR-swizzled 16B chunks (256-thread blocks).
// mode 2: global_load_lds direct (rule #21: linear dest, inverse-swizzled per-lane src).
// MAP 0: src row = rowoff+r. MAP 1: p=rowoff+r -> (p&3)*H_+(p>>2). MAP 2: p -> (p>>3)*S_+t0+(p&7).
template<int ROWS, int MAP>
__device__ __forceinline__ void stage(const void* base, int mode, int lda, int k0,
                                      int rowoff, int t0, u16* lds, int tid){
  if(mode==2){
    constexpr int NI=(ROWS*8)/256;
    int wv=tid>>6, l=tid&63;
#pragma unroll
    for(int i=0;i<NI;i++){
      int s0=i*256+(wv<<6), s=s0+l;
      int r=s>>3, gc=(s&7)^(r&7);
      int p=rowoff+r, sr;
      if(MAP==0)      sr=p;
      else if(MAP==1) sr=(p&3)*H_+(p>>2);
      else            sr=(p>>3)*S_+t0+(p&7);
      const u16* src=(const u16*)base + (size_t)sr*lda + k0 + gc*8;
      u16* dst=lds + s0*8;             // wave-uniform; HW adds lane*16B
      __builtin_amdgcn_global_load_lds((const __attribute__((address_space(1))) unsigned int*)src,
                                       (__attribute__((address_space(3))) unsigned int*)dst,
                                       16, 0, 0);
    }
  } else {
#pragma unroll
    for(int s0=tid; s0<ROWS*8; s0+=256){
      int r=s0>>3, gc=s0&7, lc=gc^(r&7);
      int p=rowoff+r, sr;
      if(MAP==0)      sr=p;
      else if(MAP==1) sr=(p&3)*H_+(p>>2);
      else            sr=(p>>3)*S_+t0+(p&7);
      f16x8 v=load8_h(base, (size_t)sr*lda + k0 + gc*8, mode);
      *(f16x8*)(lds + r*64 + lc*8)=v;
    }
  }
}

// MFMA 16x16x32 fragment from swizzled LDS tile: lane -> row r0+(l&15), chunk kc+(l>>4), un-XOR.
__device__ __forceinline__ f16x8 frag_ld(const u16* lds, int r0, int kc, int lane){
  int r = r0 + (lane&15);
  int c = (kc + (lane>>4)) ^ (r&7);
  return *(const f16x8*)(lds + r*64 + c*8);
}

// ---- device-scope grid barrier (one-shot counter per use; G16)
__device__ __forceinline__ void grid_bar(int* c, int nb){
  __builtin_amdgcn_fence(__ATOMIC_RELEASE, "agent");
  __syncthreads();
  if(threadIdx.x==0){
    __hip_atomic_fetch_add(c, 1, __ATOMIC_RELAXED, __HIP_MEMORY_SCOPE_AGENT);
    while(__hip_atomic_load(c, __ATOMIC_RELAXED, __HIP_MEMORY_SCOPE_AGENT) < nb)
      __builtin_amdgcn_s_sleep(2);
  }
  __syncthreads();
  __builtin_amdgcn_fence(__ATOMIC_ACQUIRE, "agent");
}

// ---- 128x128-tile GEMM: C = A * B^T + biasf. amode/bmode: <0 -> *flag, else literal.
// OUTMODE 0: relu, fp16 out. OUTMODE 1: fp32 out.
template<int AMAP, int BMAP, int OUTMODE>
__global__ __launch_bounds__(256,3) void gemm128(const void* A, const void* Bt, void* C,
    const float* __restrict__ biasf, const int* __restrict__ flag,
    int K, int lda, int ldb, int ldc, int t0, int amode, int bmode){
  int m=*flag;
  int am = amode<0 ? m : amode;
  int bm_ = bmode<0 ? m : bmode;
  __shared__ u16 As[128*64];
  __shared__ u16 Bs[128*64];
  int tid=threadIdx.x, lane=tid&63, w=tid>>6;
  int bm=blockIdx.y*128, bn=blockIdx.x*128;
  int wm=(w&1)*64, wn=(w>>1)*64;
  f32x4 acc[4][4];
#pragma unroll
  for(int i=0;i<4;i++)
#pragma unroll
    for(int j=0;j<4;j++) acc[i][j]=(f32x4)(0.f);
  for(int k0=0;k0<K;k0+=64){
    stage<128,AMAP>(A , am,  lda, k0, bm, t0, As, tid);
    stage<128,BMAP>(Bt, bm_, ldb, k0, bn, t0, Bs, tid);
    __syncthreads();
#pragma unroll
    for(int kk=0;kk<2;kk++){
      f16x8 af[4], bq[4];
#pragma unroll
      for(int i=0;i<4;i++) af[i]=frag_ld(As, wm+i*16, kk*4, lane);
#pragma unroll
      for(int j=0;j<4;j++) bq[j]=frag_ld(Bs, wn+j*16, kk*4, lane);
#pragma unroll
      for(int i=0;i<4;i++)
#pragma unroll
        for(int j=0;j<4;j++)
          acc[i][j]=__builtin_amdgcn_mfma_f32_16x16x32_f16(af[i],bq[j],acc[i][j],0,0,0);
    }
    __syncthreads();
  }
  int rl=lane>>4, cl=lane&15;
#pragma unroll
  for(int j=0;j<4;j++){
    int col=bn+wn+j*16+cl;
    float bb=biasf[col];
#pragma unroll
    for(int i=0;i<4;i++){
#pragma unroll
      for(int r=0;r<4;r++){
        int row=bm+wm+i*16+rl*4+r;
        float v=acc[i][j][r]+bb;
        if(OUTMODE==0){ v=fmaxf(v,0.f); ((u16*)C)[(size_t)row*ldc+col]=f2h(v); }
        else          { ((float*)C)[(size_t)row*ldc+col]=v; }
      }
    }
  }
}

// ---- persistent chunk-LSTM v2: Whh in REGISTERS, h-slice in LDS, 512 threads.
// Grid 256 = 4 batch-groups x 64 col-groups; block = 64 batches x 64 gate cols.
// Wave w (0..7): col-half ch=w>>2 (32 cols), K-quarter q=w&3 (256 K).
// BP 0: Whh_ = pre-converted permuted fp16. BP 1: raw Whh (mode *flag, permute rows).
template<int BP>
__global__ __launch_bounds__(512,1) void lstm_persist(u16* __restrict__ hh,
        const void* __restrict__ Whh_, const float* __restrict__ xg,
        float* __restrict__ cst, int* __restrict__ cnt7, const int* __restrict__ flag){
  __shared__ u16 As[16*64*64];    // 128 KB: full h-slice, 16 k-tiles of [64][64] swizzled
  __shared__ float gs[64*64];     // 16 KB gate accum
  int tid=threadIdx.x, lane=tid&63, w=tid>>6;
  int q=w&3, ch=w>>2;
  int g=(blockIdx.x&7)*32 + (blockIdx.x>>3);   // XCD swizzle
  int bm=(g>>6)*64, bn=(g&63)*64;
  int m = (BP==1) ? *flag : 2;

  // ---- Whh slice -> registers: b[c][t], c=2 col-tiles of 16, t=8 k-subtiles of 32.
  f16x8 b[2][8];
#pragma unroll
  for(int c=0;c<2;c++){
#pragma unroll
    for(int t=0;t<8;t++){
      int row = bn + ch*32 + c*16 + (lane&15);
      int k   = q*256 + t*32 + (lane>>4)*8;
      if(BP==0) b[c][t]=*(const f16x8*)((const u16*)Whh_ + (size_t)row*H_ + k);
      else{ int sr=(row&3)*H_+(row>>2); b[c][t]=load8_h(Whh_, (size_t)sr*H_ + k, m); }
    }
  }
  // ---- c-state -> registers for the whole chunk (thread owns cells tid, tid+512)
  int rl0=tid>>4,        u0=tid&15;
  int rl1=(tid+512)>>4,  u1=tid&15;
  int gu0=(bn>>2)+u0, gu1=(bn>>2)+u1;
  float c0=cst[(size_t)(bm+rl0)*H_+gu0];
  float c1=cst[(size_t)(bm+rl1)*H_+gu1];

  for(int dt=0;dt<CH_;dt++){
    if(dt) grid_bar(cnt7+dt-1, 256);
    // ---- one-burst stage of h_prev[64][1024] (16 k-tiles, 1 gload_lds each per thread)
    {
      int slotPrev=(dt+7)&7;
      int s=tid, r=s>>3, gc=(s&7)^(r&7);
      const u16* srow = hh + ((size_t)(bm+r)*CH_ + slotPrev)*H_ + gc*8;
      u16* dst = As + (tid>>6)*512;      // wave-uniform; HW adds lane*16B
#pragma unroll
      for(int kt=0;kt<16;kt++){
        __builtin_amdgcn_global_load_lds((const __attribute__((address_space(1))) unsigned int*)(srow + kt*64),
                                         (__attribute__((address_space(3))) unsigned int*)(dst + kt*4096),
                                         16, 0, 0);
      }
    }
    // xg slice -> regs (overlaps with stage; each thread owns gs cells tid*8..+7)
    int xrl=tid>>3, xcl=(tid&7)*8;
    const float* xp = xg + ((size_t)(bm+xrl)*CH_+dt)*G_ + bn + xcl;
    float4 xa=*(const float4*)xp, xb=*(const float4*)(xp+4);
    __syncthreads();                     // As ready (vmcnt0 drain), gs free
    // gs init = xg
    *(float4*)&gs[xrl*64+xcl]=xa; *(float4*)&gs[xrl*64+xcl+4]=xb;
    // ---- MFMA: acc[m][c] over wave's K-quarter
    f32x4 acc[4][2];
#pragma unroll
    for(int i=0;i<4;i++){ acc[i][0]=(f32x4)(0.f); acc[i][1]=(f32x4)(0.f); }
#pragma unroll
    for(int tg=0;tg<4;tg++){
#pragma unroll
      for(int kk=0;kk<2;kk++){
        f16x8 af[4];
#pragma unroll
        for(int i=0;i<4;i++) af[i]=frag_ld(As+(q*4+tg)*4096, i*16, kk*4, lane);
#pragma unroll
        for(int i=0;i<4;i++){
          acc[i][0]=__builtin_amdgcn_mfma_f32_16x16x32_f16(af[i],b[0][tg*2+kk],acc[i][0],0,0,0);
          acc[i][1]=__builtin_amdgcn_mfma_f32_16x16x32_f16(af[i],b[1][tg*2+kk],acc[i][1],0,0,0);
        }
      }
    }
    __syncthreads();                     // gs init visible; accs done
    // ---- K-reduction: 4 phases, waves with q==p add their partials
#pragma unroll
    for(int p=0;p<4;p++){
      if(q==p){
#pragma unroll
        for(int i=0;i<4;i++){
#pragma unroll
          for(int c=0;c<2;c++){
#pragma unroll
            for(int r=0;r<4;r++){
              int row=i*16+(lane>>4)*4+r;
              int col=ch*32+c*16+(lane&15);
              gs[row*64+col]+=acc[i][c][r];
            }
          }
        }
      }
      __syncthreads();
    }
    // ---- elementwise (2 cells/thread), c in regs, h -> hh[dt]
    {
      float4 gv=*(const float4*)&gs[rl0*64+u0*4];
      float ii=1.f/(1.f+__expf(-gv.x));
      float ff=1.f/(1.f+__expf(-gv.y));
      float gg=1.f-2.f/(__expf(2.f*gv.z)+1.f);
      float oo=1.f/(1.f+__expf(-gv.w));
      c0=ff*c0+ii*gg;
      float th=1.f-2.f/(__expf(2.f*c0)+1.f);
      hh[(size_t)(bm+rl0)*(CH_*H_) + dt*H_ + gu0]=f2h(oo*th);
    }
    {
      float4 gv=*(const float4*)&gs[rl1*64+u1*4];
      float ii=1.f/(1.f+__expf(-gv.x));
      float ff=1.f/(1.f+__expf(-gv.y));
      float gg=1.f-2.f/(__expf(2.f*gv.z)+1.f);
      float oo=1.f/(1.f+__expf(-gv.w));
      c1=ff*c1+ii*gg;
      float th=1.f-2.f/(__expf(2.f*c1)+1.f);
      hh[(size_t)(bm+rl1)*(CH_*H_) + dt*H_ + gu1]=f2h(oo*th);
    }
    // next iteration's grid_bar __syncthreads orders gs reads vs next gs init
  }
  cst[(size_t)(bm+rl0)*H_+gu0]=c0;
  cst[(size_t)(bm+rl1)*H_+gu1]=c1;
}

// ---- heads for one chunk: wave per row rg=b*8+dt; output gw=b*S+t0+dt.
__global__ __launch_bounds__(256,2) void heads_chunk(const u16* __restrict__ hh,
      const void* __restrict__ Wl, const void* __restrict__ Wv,
      const float* __restrict__ blf, const int* __restrict__ acts,
      void* __restrict__ out, const int* __restrict__ flag, int t0){
  int m=*flag;
  int rg = blockIdx.x*4 + (threadIdx.x>>6);
  int lane = threadIdx.x & 63;
  const u16* h = hh + (size_t)rg*H_;               // fp16
  f16x8 h0=*(const f16x8*)(h + lane*16), h1=*(const f16x8*)(h + lane*16 + 8);
  float hv[16];
#pragma unroll
  for(int k=0;k<8;k++){ hv[k]=(float)h0[k]; hv[8+k]=(float)h1[k]; }
  float dots[19];
#pragma unroll
  for(int j=0;j<19;j++){
    const void* wrow = (j<18) ? Wl : Wv;
    size_t roff = (j<18) ? (size_t)j*H_ : 0;
    float wv_[16];
    if(m){
      const float* f=(const float*)wrow + roff + lane*16;
      float4 a=*(const float4*)f, b=*(const float4*)(f+4), c=*(const float4*)(f+8), d=*(const float4*)(f+12);
      wv_[0]=a.x;wv_[1]=a.y;wv_[2]=a.z;wv_[3]=a.w; wv_[4]=b.x;wv_[5]=b.y;wv_[6]=b.z;wv_[7]=b.w;
      wv_[8]=c.x;wv_[9]=c.y;wv_[10]=c.z;wv_[11]=c.w; wv_[12]=d.x;wv_[13]=d.y;wv_[14]=d.z;wv_[15]=d.w;
    } else {
      const u16* ub=(const u16*)wrow + roff + lane*16;
      s16x8 w0=*(const s16x8*)ub, w1=*(const s16x8*)(ub+8);
#pragma unroll
      for(int k=0;k<8;k++){ wv_[k]=bf2f((u16)w0[k]); wv_[8+k]=bf2f((u16)w1[k]); }
    }
    float d=0.f;
#pragma unroll
    for(int k=0;k<16;k++) d += hv[k]*wv_[k];
#pragma unroll
    for(int mm=1;mm<64;mm<<=1) d += __shfl_xor(d, mm, 64);
    dots[j]=d;
  }
  float lg[18];
#pragma unroll
  for(int j=0;j<18;j++) lg[j]=dots[j]+blf[j];
  float value=dots[18]+blf[18];
  float mx=lg[0];
#pragma unroll
  for(int j=1;j<18;j++) mx=fmaxf(mx,lg[j]);
  float se=0.f, s1=0.f;
#pragma unroll
  for(int j=0;j<18;j++){ float e=__expf(lg[j]-mx); se+=e; s1+=e*(lg[j]-mx); }
  float lse=__logf(se);
  int b=rg>>3, dt=rg&7;
  int gw = b*S_ + t0 + dt;
  int a=acts[gw];
  float la=0.f;
#pragma unroll
  for(int j=0;j<18;j++) la = (j==a) ? lg[j] : la;
  float lp=la-mx-lse;
  float ent=lse - s1/se;
  if(lane==0){
    if(m){
      ((float*)out)[gw]=lp; ((float*)out)[M_+gw]=ent; ((float*)out)[2*M_+gw]=value;
    } else {
      ((u16*)out)[gw]=f2bf(lp); ((u16*)out)[M_+gw]=f2bf(ent); ((u16*)out)[2*M_+gw]=f2bf(value);
    }
  }
}

// ---- dtype detect
__global__ void detect(const u16* __restrict__ obs_w, int* __restrict__ flag){
  __shared__ float red[256];
  float mx=0.f;
  for(int i=threadIdx.x;i<4096;i+=256) mx=fmaxf(mx,fabsf(bf2f(obs_w[i])));
  red[threadIdx.x]=mx; __syncthreads();
  for(int s=128;s>0;s>>=1){
    if(threadIdx.x<s) red[threadIdx.x]=fmaxf(red[threadIdx.x],red[threadIdx.x+s]);
    __syncthreads();
  }
  if(threadIdx.x==0) *flag=(red[0]>1e4f)?1:0;
}

// ---- prep: biases, c state, h seed (fp16, slot 7), zero barrier counters.
__global__ void prep(const void* bih, const void* bhh, const void* b1, const void* bl, const void* bv,
                     const void* cx, const void* hx,
                     float* biasg, float* b1f, float* blf, float* cst, u16* hh,
                     int* cnt, const int* __restrict__ flag){
  int m=*flag;
  size_t i=(size_t)blockIdx.x*256+threadIdx.x;
  if(i<G_){ size_t rm=(i&3)*H_+(i>>2); biasg[i]=ldf(bih,rm,m)+ldf(bhh,rm,m); return; }
  i-=G_;
  if(i<H_){ b1f[i]=ldf(b1,i,m); return; }
  i-=H_;
  if(i<19){ blf[i]=(i<18)?ldf(bl,i,m):ldf(bv,0,m); return; }
  i-=19;
  if(i<128){ cnt[i]=0; return; }
  i-=128;
  if(i<(size_t)B_*H_){ cst[i]=ldf(cx,i,m); return; }
  i-=(size_t)B_*H_;
  if(i<(size_t)B_*H_){
    size_t b=i>>10, k=i&1023;
    hh[b*(CH_*H_) + 7*H_ + k]=f2h(ldf(hx,i,m));
  }
}

// ---- weight pre-conversion to fp16 (exact from bf16), gate-permuted for Wih/Whh.
__global__ void convw(const void* W1, const void* Wih, const void* Whh,
                      u16* W1h, u16* Wihp, u16* Whhp, const int* __restrict__ flag){
  int m=*flag;
  size_t i=((size_t)blockIdx.x*256+threadIdx.x)*8;
  const size_t n1=(size_t)H_*F_, n2=(size_t)G_*H_;
  if(i<n1){ *(f16x8*)(W1h+i)=load8_h(W1,i,m); return; }
  i-=n1;
  if(i<n2){ size_t p=i>>10, c=i&1023; size_t sr=(p&3)*H_+(p>>2);
            *(f16x8*)(Wihp+i)=load8_h(Wih, sr*H_+c, m); return; }
  i-=n2;
  if(i<n2){ size_t p=i>>10, c=i&1023; size_t sr=(p&3)*H_+(p>>2);
            *(f16x8*)(Whhp+i)=load8_h(Whh, sr*H_+c, m); return; }
}
__global__ void convobs(const void* obs, u16* obsh, const int* __restrict__ flag){
  int m=*flag;
  size_t i=((size_t)blockIdx.x*256+threadIdx.x)*8;
  if(i<(size_t)M_*F_) *(f16x8*)(obsh+i)=load8_h(obs,i,m);
}

extern "C" void kernel_launch(void* const* d_in, const int* in_sizes, int n_in,
                              void* d_out, int out_size, void* d_ws, size_t ws_size,
                              hipStream_t stream){
  const void* obs=d_in[0];
  const void* hx =d_in[1];
  const void* cx =d_in[2];
  const int* acts=(const int*)d_in[3];
  const void* W1 =d_in[4];
  const void* b1 =d_in[5];
  const void* Wih=d_in[6];
  const void* bih=d_in[7];
  const void* Whh=d_in[8];
  const void* bhh=d_in[9];
  const void* Wv =d_in[10];
  const void* bv =d_in[11];
  const void* Wl =d_in[12];
  const void* bl =d_in[13];

  char* w=(char*)d_ws;
  auto alloc=[&](size_t n){ char* p=w; w+=((n+255)&~(size_t)255); return p; };
  int*   flag =(int*)alloc(4);
  int*   cnt  =(int*)alloc(128*4);                 // 16 chunks x up to 8 barriers
  float* biasg=(float*)alloc((size_t)G_*4);
  float* b1f  =(float*)alloc((size_t)H_*4);
  float* blf  =(float*)alloc(32*4);
  float* cst  =(float*)alloc((size_t)B_*H_*4);     // 1 MB fp32 c
  u16*   hh   =(u16*)alloc((size_t)B_*CH_*H_*2);   // 4 MB fp16 h history
  u16*   xc   =(u16*)alloc((size_t)CR_*H_*2);      // 4 MB fp16 x chunk
  float* xg   =(float*)alloc((size_t)CR_*G_*4);    // 32 MB fp32 xg chunk
  // tiers
  size_t nW=((size_t)H_*F_ + 2*(size_t)G_*H_)*2 + 768;
  bool pathW = ((size_t)(w-(char*)d_ws) + nW) <= ws_size;
  u16 *W1h=0,*Wihp=0,*Whhp=0;
  if(pathW){ W1h=(u16*)alloc((size_t)H_*F_*2); Wihp=(u16*)alloc((size_t)G_*H_*2); Whhp=(u16*)alloc((size_t)G_*H_*2); }
  size_t nXC=(size_t)M_*H_*2 + 256;
  bool pathXC = pathW && (((size_t)(w-(char*)d_ws) + nXC) <= ws_size);
  u16* xcf=0; if(pathXC) xcf=(u16*)alloc((size_t)M_*H_*2);
  size_t nO=(size_t)M_*F_*2 + 256;
  bool pathO = pathXC && (((size_t)(w-(char*)d_ws) + nO) <= ws_size);
  u16* obsh=0; if(pathO) obsh=(u16*)alloc((size_t)M_*F_*2);

  detect<<<1,256,0,stream>>>((const u16*)obs, flag);
  {
    int total=G_+H_+19+128+B_*H_+B_*H_;
    prep<<<(total+255)/256,256,0,stream>>>(bih,bhh,b1,bl,bv,cx,hx, biasg,b1f,blf,cst,hh,cnt, flag);
  }
  if(pathW){
    size_t n=((size_t)H_*F_+2*(size_t)G_*H_)/8;
    convw<<<(int)((n+255)/256),256,0,stream>>>(W1,Wih,Whh, W1h,Wihp,Whhp, flag);
  }
  if(pathO){
    size_t n=(size_t)M_*F_/8;
    convobs<<<(int)((n+255)/256),256,0,stream>>>(obs, obsh, flag);
  }
  if(pathXC){
    gemm128<0,0,0><<<dim3(H_/128, M_/128),256,0,stream>>>(
        pathO?(const void*)obsh:obs, pathW?(const void*)W1h:W1, xcf, b1f, flag,
        F_, F_, F_, H_, 0, pathO?2:-1, pathW?2:-1);
  }

  for(int c=0;c<S_/CH_;c++){
    int t0=c*CH_;
    if(!pathXC){
      gemm128<2,0,0><<<dim3(H_/128, CR_/128),256,0,stream>>>(
          obs, pathW?(const void*)W1h:W1, xc, b1f, flag, F_, F_, F_, H_, t0, -1, pathW?2:-1);
    }
    if(pathXC)
      gemm128<2,0,1><<<dim3(G_/128, CR_/128),256,0,stream>>>(
          xcf, Wihp, xg, biasg, flag, H_, H_, H_, G_, t0, 2, 2);
    else if(pathW)
      gemm128<0,0,1><<<dim3(G_/128, CR_/128),256,0,stream>>>(
          xc, Wihp, xg, biasg, flag, H_, H_, H_, G_, 0, 2, 2);
    else
      gemm128<0,1,1><<<dim3(G_/128, CR_/128),256,0,stream>>>(
          xc, Wih, xg, biasg, flag, H_, H_, H_, G_, 0, 2, -1);

    if(pathW)
      lstm_persist<0><<<256,512,0,stream>>>(hh, Whhp, xg, cst, cnt+c*8, flag);
    else
      lstm_persist<1><<<256,512,0,stream>>>(hh, Whh,  xg, cst, cnt+c*8, flag);

    heads_chunk<<<dim3(CR_/4),256,0,stream>>>(hh, Wl, Wv, blf, acts, d_out, flag, t0);
  }
}

// Round 7
// 1893.315 us; speedup vs baseline: 3.6427x; 3.6427x over previous
//
#include <hip/hip_runtime.h>

#define B_ 256
#define S_ 128
#define F_ 512
#define H_ 1024
#define A_ 18
#define M_ (B_*S_)      // 32768 output rows (b*S+s)
#define G_ (4*H_)       // 4096 gate cols, permuted unit-major: p = unit*4 + {i,f,g,o}
#define CH_ 8           // timesteps per chunk
#define CR_ (B_*CH_)    // 2048 rows per chunk, row rg = b*CH_ + dt

typedef unsigned short u16;
typedef __attribute__((ext_vector_type(8))) _Float16 f16x8;  // 8 fp16 = 4 VGPR
typedef __attribute__((ext_vector_type(8))) short   s16x8;
typedef __attribute__((ext_vector_type(4))) float f32x4;
typedef __attribute__((ext_vector_type(4))) unsigned int u32x4;

__device__ __forceinline__ float bf2f(u16 u){
  union{unsigned int i; float f;} v; v.i=((unsigned int)u)<<16; return v.f;
}
__device__ __forceinline__ u16 f2bf(float f){
  unsigned int i=__float_as_uint(f);
  unsigned int r=(i+0x7fffu+((i>>16)&1u))>>16;   // RNE
  return (u16)r;
}
__device__ __forceinline__ u16 f2h(float f){
  _Float16 h=(_Float16)f;
  union{_Float16 h; u16 u;} v; v.h=h; return v.u;
}
// mode-aware scalar load of logical float element i (1: fp32, 0: bf16)
__device__ __forceinline__ float ldf(const void* p, size_t i, int m){
  return m ? ((const float*)p)[i] : bf2f(((const u16*)p)[i]);
}
// load 8 logical floats -> fp16x8. mode 0: bf16 src, 1: fp32 src, 2: raw fp16 src.
__device__ __forceinline__ f16x8 load8_h(const void* base, size_t off, int m){
  f16x8 v;
  if(m==2) return *(const f16x8*)((const u16*)base + off);
  if(m==1){
    const float* f=(const float*)base + off;
    float4 a=*(const float4*)f; float4 b=*(const float4*)(f+4);
    v[0]=(_Float16)a.x; v[1]=(_Float16)a.y; v[2]=(_Float16)a.z; v[3]=(_Float16)a.w;
    v[4]=(_Float16)b.x; v[5]=(_Float16)b.y; v[6]=(_Float16)b.z; v[7]=(_Float16)b.w;
    return v;
  }
  s16x8 w=*(const s16x8*)((const u16*)base + off);
#pragma unroll
  for(int k=0;k<8;k++) v[k]=(_Float16)bf2f((u16)w[k]);
  return v;
}

// ---- coherent (cross-XCD, LLC-routed) 16B load / 2B store: bypass L1+L2 via sc0 sc1.
__device__ __forceinline__ u32x4 load_c16(const void* p){
  u32x4 r;
  asm volatile("global_load_dwordx4 %0, %1, off sc0 sc1" : "=v"(r) : "v"(p));
  return r;
}
__device__ __forceinline__ void store_c2(u16* p, u16 v){
  unsigned int vv=v;
  asm volatile("global_store_short %0, %1, off sc0 sc1" :: "v"(p), "v"(vv) : "memory");
}

// ---- fence-free grid barrier: own stores drained -> block sync -> relaxed agent atomic.
// hh traffic is sc0/sc1 (coherent at LLC), so NO agent fence (no L2 wb/inv) is needed.
__device__ __forceinline__ void bar_lite(int* c, int nb){
  asm volatile("s_waitcnt vmcnt(0)" ::: "memory");
  __syncthreads();
  if(threadIdx.x==0){
    __hip_atomic_fetch_add(c,1,__ATOMIC_RELAXED,__HIP_MEMORY_SCOPE_AGENT);
    while(__hip_atomic_load(c,__ATOMIC_RELAXED,__HIP_MEMORY_SCOPE_AGENT)<nb)
      __builtin_amdgcn_s_sleep(1);
  }
  __syncthreads();
}

// ---- Stage ROWS x 64 fp16 tile into LDS [ROWS][64], XOR-swizzled 16B chunks (256-thr blocks).
// mode 2: global_load_lds direct (linear dest, inverse-swizzled per-lane src).
// MAP 0: src row = rowoff+r. MAP 1: p=rowoff+r -> (p&3)*H_+(p>>2). MAP 2: p -> (p>>3)*S_+t0+(p&7).
template<int ROWS, int MAP>
__device__ __forceinline__ void stage(const void* base, int mode, int lda, int k0,
                                      int rowoff, int t0, u16* lds, int tid){
  if(mode==2){
    constexpr int NI=(ROWS*8)/256;
    int wv=tid>>6, l=tid&63;
#pragma unroll
    for(int i=0;i<NI;i++){
      int s0=i*256+(wv<<6), s=s0+l;
      int r=s>>3, gc=(s&7)^(r&7);
      int p=rowoff+r, sr;
      if(MAP==0)      sr=p;
      else if(MAP==1) sr=(p&3)*H_+(p>>2);
      else            sr=(p>>3)*S_+t0+(p&7);
      const u16* src=(const u16*)base + (size_t)sr*lda + k0 + gc*8;
      u16* dst=lds + s0*8;             // wave-uniform; HW adds lane*16B
      __builtin_amdgcn_global_load_lds((const __attribute__((address_space(1))) unsigned int*)src,
                                       (__attribute__((address_space(3))) unsigned int*)dst,
                                       16, 0, 0);
    }
  } else {
#pragma unroll
    for(int s0=tid; s0<ROWS*8; s0+=256){
      int r=s0>>3, gc=s0&7, lc=gc^(r&7);
      int p=rowoff+r, sr;
      if(MAP==0)      sr=p;
      else if(MAP==1) sr=(p&3)*H_+(p>>2);
      else            sr=(p>>3)*S_+t0+(p&7);
      f16x8 v=load8_h(base, (size_t)sr*lda + k0 + gc*8, mode);
      *(f16x8*)(lds + r*64 + lc*8)=v;
    }
  }
}

// MFMA 16x16x32 fragment from swizzled LDS tile: lane -> row r0+(l&15), chunk kc+(l>>4), un-XOR.
__device__ __forceinline__ f16x8 frag_ld(const u16* lds, int r0, int kc, int lane){
  int r = r0 + (lane&15);
  int c = (kc + (lane>>4)) ^ (r&7);
  return *(const f16x8*)(lds + r*64 + c*8);
}

// ---- 128x128-tile GEMM: C = A * B^T + biasf. amode/bmode: <0 -> *flag, else literal.
// OUTMODE 0: relu, fp16 out. OUTMODE 1: fp32 out.
template<int AMAP, int BMAP, int OUTMODE>
__global__ __launch_bounds__(256,3) void gemm128(const void* A, const void* Bt, void* C,
    const float* __restrict__ biasf, const int* __restrict__ flag,
    int K, int lda, int ldb, int ldc, int t0, int amode, int bmode){
  int m=*flag;
  int am = amode<0 ? m : amode;
  int bm_ = bmode<0 ? m : bmode;
  __shared__ u16 As[128*64];
  __shared__ u16 Bs[128*64];
  int tid=threadIdx.x, lane=tid&63, w=tid>>6;
  int bm=blockIdx.y*128, bn=blockIdx.x*128;
  int wm=(w&1)*64, wn=(w>>1)*64;
  f32x4 acc[4][4];
#pragma unroll
  for(int i=0;i<4;i++)
#pragma unroll
    for(int j=0;j<4;j++) acc[i][j]=(f32x4)(0.f);
  for(int k0=0;k0<K;k0+=64){
    stage<128,AMAP>(A , am,  lda, k0, bm, t0, As, tid);
    stage<128,BMAP>(Bt, bm_, ldb, k0, bn, t0, Bs, tid);
    __syncthreads();
#pragma unroll
    for(int kk=0;kk<2;kk++){
      f16x8 af[4], bq[4];
#pragma unroll
      for(int i=0;i<4;i++) af[i]=frag_ld(As, wm+i*16, kk*4, lane);
#pragma unroll
      for(int j=0;j<4;j++) bq[j]=frag_ld(Bs, wn+j*16, kk*4, lane);
#pragma unroll
      for(int i=0;i<4;i++)
#pragma unroll
        for(int j=0;j<4;j++)
          acc[i][j]=__builtin_amdgcn_mfma_f32_16x16x32_f16(af[i],bq[j],acc[i][j],0,0,0);
    }
    __syncthreads();
  }
  int rl=lane>>4, cl=lane&15;
#pragma unroll
  for(int j=0;j<4;j++){
    int col=bn+wn+j*16+cl;
    float bb=biasf[col];
#pragma unroll
    for(int i=0;i<4;i++){
#pragma unroll
      for(int r=0;r<4;r++){
        int row=bm+wm+i*16+rl*4+r;
        float v=acc[i][j][r]+bb;
        if(OUTMODE==0){ v=fmaxf(v,0.f); ((u16*)C)[(size_t)row*ldc+col]=f2h(v); }
        else          { ((float*)C)[(size_t)row*ldc+col]=v; }
      }
    }
  }
}

// ---- persistent chunk-LSTM v3: fence-free barriers, coherent h via LLC, Whh in regs.
// Grid 256 (1/CU), 512 threads. Block: 64 batches x 64 gate cols.
// Wave w: mh=w&1 (32-row grp), ch=(w>>1)&1 (32-col grp), q=w>>2 (512-K half).
// Whh regs: b[2][16] f16x8 = 128 VGPR/wave. Requires pre-converted permuted fp16 Whhp.
__global__ __launch_bounds__(512,2) void lstm_persist(u16* __restrict__ hh,
        const u16* __restrict__ Whhp, const float* __restrict__ xg,
        float* __restrict__ cst, int* __restrict__ cnt7){
  __shared__ u16 As[16*4096];     // 128 KB: 16 k-tiles [64][64], XOR-swizzled
  __shared__ float gs[64*68];     // 17.4 KB, pad 68 (16B-aligned rows, 2-way banks)
  int tid=threadIdx.x, lane=tid&63, w=tid>>6;
  int mh=w&1, ch=(w>>1)&1, q=w>>2;
  int g=(blockIdx.x&7)*32 + (blockIdx.x>>3);   // XCD swizzle
  int bm=(g>>6)*64, bn=(g&63)*64;

  // Whh slice -> regs: cols bn+ch*32 (2 tiles of 16), K-half q (16 subtiles of 32).
  f16x8 b[2][16];
#pragma unroll
  for(int c2=0;c2<2;c2++){
#pragma unroll
    for(int t=0;t<16;t++){
      int p = bn + ch*32 + c2*16 + (lane&15);
      int k = q*512 + t*32 + (lane>>4)*8;
      b[c2][t]=*(const f16x8*)(Whhp + (size_t)p*H_ + k);
    }
  }
  // c-state in regs for the chunk; thread owns cells tid and tid+512.
  int rl0=tid>>4, rl1=(tid+512)>>4, u0=tid&15;
  int gu=(bn>>2)+u0;
  float c0=cst[(size_t)(bm+rl0)*H_+gu];
  float c1=cst[(size_t)(bm+rl1)*H_+gu];
  // staging assignment: thread -> row sr, chunk sc (all 16 k-tiles)
  int sr=tid>>3, sc=tid&7, slc=sc^(sr&7);

  for(int dt=0;dt<CH_;dt++){
    if(dt) bar_lite(cnt7+dt-1, 256);
    // xg prefetch (normal cached loads; xg written before this kernel)
    const float* xp0=&xg[((size_t)(bm+rl0)*CH_+dt)*G_ + bn + u0*4];
    const float* xp1=&xg[((size_t)(bm+rl1)*CH_+dt)*G_ + bn + u0*4];
    float4 xv0=*(const float4*)xp0, xv1=*(const float4*)(xp1);
    // stage h_prev[64][1024]: 16 coherent 16B loads -> regs -> LDS (swizzled dest)
    {
      int slotPrev=(dt+7)&7;
      const u16* hsrc = hh + ((size_t)(bm+sr)*CH_+slotPrev)*H_ + sc*8;
      u32x4 tmp[16];
#pragma unroll
      for(int kt=0;kt<16;kt++) tmp[kt]=load_c16(hsrc + kt*64);
      asm volatile("s_waitcnt vmcnt(0)" ::: "memory");
#pragma unroll
      for(int kt=0;kt<16;kt++)
        *(u32x4*)(As + kt*4096 + sr*64 + slc*8)=tmp[kt];
    }
    __syncthreads();
    // MFMA over wave's K-half: 64 MFMA
    f32x4 acc[2][2];
#pragma unroll
    for(int i=0;i<2;i++){ acc[i][0]=(f32x4)(0.f); acc[i][1]=(f32x4)(0.f); }
#pragma unroll
    for(int t=0;t<16;t++){
      int kt=q*8+(t>>1), kk=t&1;
      f16x8 af[2];
#pragma unroll
      for(int i=0;i<2;i++) af[i]=frag_ld(As+kt*4096, mh*32+i*16, kk*4, lane);
#pragma unroll
      for(int i=0;i<2;i++){
        acc[i][0]=__builtin_amdgcn_mfma_f32_16x16x32_f16(af[i],b[0][t],acc[i][0],0,0,0);
        acc[i][1]=__builtin_amdgcn_mfma_f32_16x16x32_f16(af[i],b[1][t],acc[i][1],0,0,0);
      }
    }
    // 2-phase K reduction into gs
    if(q==0){
#pragma unroll
      for(int i=0;i<2;i++)
#pragma unroll
        for(int c2=0;c2<2;c2++)
#pragma unroll
          for(int r=0;r<4;r++)
            gs[(mh*32+i*16+(lane>>4)*4+r)*68 + ch*32+c2*16+(lane&15)]=acc[i][c2][r];
    }
    __syncthreads();
    if(q==1){
#pragma unroll
      for(int i=0;i<2;i++)
#pragma unroll
        for(int c2=0;c2<2;c2++)
#pragma unroll
          for(int r=0;r<4;r++)
            gs[(mh*32+i*16+(lane>>4)*4+r)*68 + ch*32+c2*16+(lane&15)]+=acc[i][c2][r];
    }
    __syncthreads();
    // elementwise (2 cells/thread); coherent h store (sc0 sc1 -> LLC)
    {
      float4 gv=*(const float4*)&gs[rl0*68+u0*4];
      float ii=1.f/(1.f+__expf(-(gv.x+xv0.x)));
      float ff=1.f/(1.f+__expf(-(gv.y+xv0.y)));
      float gg=1.f-2.f/(__expf(2.f*(gv.z+xv0.z))+1.f);
      float oo=1.f/(1.f+__expf(-(gv.w+xv0.w)));
      c0=ff*c0+ii*gg;
      float th=1.f-2.f/(__expf(2.f*c0)+1.f);
      store_c2(hh + (size_t)(bm+rl0)*(CH_*H_) + dt*H_ + gu, f2h(oo*th));
    }
    {
      float4 gv=*(const float4*)&gs[rl1*68+u0*4];
      float ii=1.f/(1.f+__expf(-(gv.x+xv1.x)));
      float ff=1.f/(1.f+__expf(-(gv.y+xv1.y)));
      float gg=1.f-2.f/(__expf(2.f*(gv.z+xv1.z))+1.f);
      float oo=1.f/(1.f+__expf(-(gv.w+xv1.w)));
      c1=ff*c1+ii*gg;
      float th=1.f-2.f/(__expf(2.f*c1)+1.f);
      store_c2(hh + (size_t)(bm+rl1)*(CH_*H_) + dt*H_ + gu, f2h(oo*th));
    }
  }
  cst[(size_t)(bm+rl0)*H_+gu]=c0;
  cst[(size_t)(bm+rl1)*H_+gu]=c1;
}

// ---- fallback per-step LSTM (low-ws tier): gates = xg + h_prev @ Whh(perm)^T.
__global__ __launch_bounds__(256,2) void lstm_step(u16* __restrict__ hh, int slotPrev, int dt,
        const void* __restrict__ Whh, const float* __restrict__ xg,
        float* __restrict__ cst, const int* __restrict__ flag){
  int m=*flag;
  __shared__ u16 As[64*64];
  __shared__ u16 Bs[64*64];
  __shared__ float gs[64*64];
  int tid=threadIdx.x, lane=tid&63, w=tid>>6;
  int bm=blockIdx.y*64, bn=blockIdx.x*64;
  int wm=(w&1)*32, wn=(w>>1)*32;
  f32x4 acc[2][2];
#pragma unroll
  for(int i=0;i<2;i++)
#pragma unroll
    for(int j=0;j<2;j++) acc[i][j]=(f32x4)(0.f);
  for(int k0=0;k0<H_;k0+=64){
    stage<64,0>(hh + slotPrev*H_, 2, CH_*H_, k0, bm, 0, As, tid);
    stage<64,1>(Whh,              m, H_,     k0, bn, 0, Bs, tid);
    __syncthreads();
#pragma unroll
    for(int kk=0;kk<2;kk++){
      f16x8 af[2], bq[2];
#pragma unroll
      for(int i=0;i<2;i++) af[i]=frag_ld(As, wm+i*16, kk*4, lane);
#pragma unroll
      for(int j=0;j<2;j++) bq[j]=frag_ld(Bs, wn+j*16, kk*4, lane);
#pragma unroll
      for(int i=0;i<2;i++)
#pragma unroll
        for(int j=0;j<2;j++)
          acc[i][j]=__builtin_amdgcn_mfma_f32_16x16x32_f16(af[i],bq[j],acc[i][j],0,0,0);
    }
    __syncthreads();
  }
  int rl=lane>>4, cl=lane&15;
#pragma unroll
  for(int j=0;j<2;j++){
    int coll=wn+j*16+cl;
#pragma unroll
    for(int i=0;i<2;i++){
#pragma unroll
      for(int r=0;r<4;r++){
        int rowl=wm+i*16+rl*4+r;
        gs[rowl*64+coll]=acc[i][j][r] + xg[((size_t)(bm+rowl)*CH_+dt)*G_ + bn+coll];
      }
    }
  }
  __syncthreads();
#pragma unroll
  for(int p=0;p<4;p++){
    int idx=p*256+tid;
    int rowl=idx>>4, u=idx&15;
    float4 gv = *(const float4*)&gs[rowl*64+u*4];
    float ii=1.f/(1.f+__expf(-gv.x));
    float ff=1.f/(1.f+__expf(-gv.y));
    float gg=1.f-2.f/(__expf(2.f*gv.z)+1.f);
    float oo=1.f/(1.f+__expf(-gv.w));
    int gb=bm+rowl;
    int gu=(bn>>2)+u;
    size_t ci=(size_t)gb*H_+gu;
    float cn=ff*cst[ci]+ii*gg;
    cst[ci]=cn;
    float th=1.f-2.f/(__expf(2.f*cn)+1.f);
    hh[(size_t)gb*(CH_*H_) + dt*H_ + gu]=f2h(oo*th);
  }
}

// ---- heads for one chunk: wave per row rg=b*8+dt; output gw=b*S+t0+dt.
__global__ __launch_bounds__(256,2) void heads_chunk(const u16* __restrict__ hh,
      const void* __restrict__ Wl, const void* __restrict__ Wv,
      const float* __restrict__ blf, const int* __restrict__ acts,
      void* __restrict__ out, const int* __restrict__ flag, int t0){
  int m=*flag;
  int rg = blockIdx.x*4 + (threadIdx.x>>6);
  int lane = threadIdx.x & 63;
  const u16* h = hh + (size_t)rg*H_;               // fp16
  f16x8 h0=*(const f16x8*)(h + lane*16), h1=*(const f16x8*)(h + lane*16 + 8);
  float hv[16];
#pragma unroll
  for(int k=0;k<8;k++){ hv[k]=(float)h0[k]; hv[8+k]=(float)h1[k]; }
  float dots[19];
#pragma unroll
  for(int j=0;j<19;j++){
    const void* wrow = (j<18) ? Wl : Wv;
    size_t roff = (j<18) ? (size_t)j*H_ : 0;
    float wv_[16];
    if(m){
      const float* f=(const float*)wrow + roff + lane*16;
      float4 a=*(const float4*)f, b=*(const float4*)(f+4), c=*(const float4*)(f+8), d=*(const float4*)(f+12);
      wv_[0]=a.x;wv_[1]=a.y;wv_[2]=a.z;wv_[3]=a.w; wv_[4]=b.x;wv_[5]=b.y;wv_[6]=b.z;wv_[7]=b.w;
      wv_[8]=c.x;wv_[9]=c.y;wv_[10]=c.z;wv_[11]=c.w; wv_[12]=d.x;wv_[13]=d.y;wv_[14]=d.z;wv_[15]=d.w;
    } else {
      const u16* ub=(const u16*)wrow + roff + lane*16;
      s16x8 w0=*(const s16x8*)ub, w1=*(const s16x8*)(ub+8);
#pragma unroll
      for(int k=0;k<8;k++){ wv_[k]=bf2f((u16)w0[k]); wv_[8+k]=bf2f((u16)w1[k]); }
    }
    float d=0.f;
#pragma unroll
    for(int k=0;k<16;k++) d += hv[k]*wv_[k];
#pragma unroll
    for(int mm=1;mm<64;mm<<=1) d += __shfl_xor(d, mm, 64);
    dots[j]=d;
  }
  float lg[18];
#pragma unroll
  for(int j=0;j<18;j++) lg[j]=dots[j]+blf[j];
  float value=dots[18]+blf[18];
  float mx=lg[0];
#pragma unroll
  for(int j=1;j<18;j++) mx=fmaxf(mx,lg[j]);
  float se=0.f, s1=0.f;
#pragma unroll
  for(int j=0;j<18;j++){ float e=__expf(lg[j]-mx); se+=e; s1+=e*(lg[j]-mx); }
  float lse=__logf(se);
  int b=rg>>3, dt=rg&7;
  int gw = b*S_ + t0 + dt;
  int a=acts[gw];
  float la=0.f;
#pragma unroll
  for(int j=0;j<18;j++) la = (j==a) ? lg[j] : la;
  float lp=la-mx-lse;
  float ent=lse - s1/se;
  if(lane==0){
    if(m){
      ((float*)out)[gw]=lp; ((float*)out)[M_+gw]=ent; ((float*)out)[2*M_+gw]=value;
    } else {
      ((u16*)out)[gw]=f2bf(lp); ((u16*)out)[M_+gw]=f2bf(ent); ((u16*)out)[2*M_+gw]=f2bf(value);
    }
  }
}

// ---- dtype detect
__global__ void detect(const u16* __restrict__ obs_w, int* __restrict__ flag){
  __shared__ float red[256];
  float mx=0.f;
  for(int i=threadIdx.x;i<4096;i+=256) mx=fmaxf(mx,fabsf(bf2f(obs_w[i])));
  red[threadIdx.x]=mx; __syncthreads();
  for(int s=128;s>0;s>>=1){
    if(threadIdx.x<s) red[threadIdx.x]=fmaxf(red[threadIdx.x],red[threadIdx.x+s]);
    __syncthreads();
  }
  if(threadIdx.x==0) *flag=(red[0]>1e4f)?1:0;
}

// ---- prep: biases, c state, h seed (fp16, slot 7), zero barrier counters.
__global__ void prep(const void* bih, const void* bhh, const void* b1, const void* bl, const void* bv,
                     const void* cx, const void* hx,
                     float* biasg, float* b1f, float* blf, float* cst, u16* hh,
                     int* cnt, const int* __restrict__ flag){
  int m=*flag;
  size_t i=(size_t)blockIdx.x*256+threadIdx.x;
  if(i<G_){ size_t rm=(i&3)*H_+(i>>2); biasg[i]=ldf(bih,rm,m)+ldf(bhh,rm,m); return; }
  i-=G_;
  if(i<H_){ b1f[i]=ldf(b1,i,m); return; }
  i-=H_;
  if(i<19){ blf[i]=(i<18)?ldf(bl,i,m):ldf(bv,0,m); return; }
  i-=19;
  if(i<128){ cnt[i]=0; return; }
  i-=128;
  if(i<(size_t)B_*H_){ cst[i]=ldf(cx,i,m); return; }
  i-=(size_t)B_*H_;
  if(i<(size_t)B_*H_){
    size_t b=i>>10, k=i&1023;
    hh[b*(CH_*H_) + 7*H_ + k]=f2h(ldf(hx,i,m));
  }
}

// ---- weight pre-conversion to fp16 (exact from bf16), gate-permuted for Wih/Whh.
__global__ void convw(const void* W1, const void* Wih, const void* Whh,
                      u16* W1h, u16* Wihp, u16* Whhp, const int* __restrict__ flag){
  int m=*flag;
  size_t i=((size_t)blockIdx.x*256+threadIdx.x)*8;
  const size_t n1=(size_t)H_*F_, n2=(size_t)G_*H_;
  if(i<n1){ *(f16x8*)(W1h+i)=load8_h(W1,i,m); return; }
  i-=n1;
  if(i<n2){ size_t p=i>>10, c=i&1023; size_t sr=(p&3)*H_+(p>>2);
            *(f16x8*)(Wihp+i)=load8_h(Wih, sr*H_+c, m); return; }
  i-=n2;
  if(i<n2){ size_t p=i>>10, c=i&1023; size_t sr=(p&3)*H_+(p>>2);
            *(f16x8*)(Whhp+i)=load8_h(Whh, sr*H_+c, m); return; }
}
__global__ void convobs(const void* obs, u16* obsh, const int* __restrict__ flag){
  int m=*flag;
  size_t i=((size_t)blockIdx.x*256+threadIdx.x)*8;
  if(i<(size_t)M_*F_) *(f16x8*)(obsh+i)=load8_h(obs,i,m);
}

extern "C" void kernel_launch(void* const* d_in, const int* in_sizes, int n_in,
                              void* d_out, int out_size, void* d_ws, size_t ws_size,
                              hipStream_t stream){
  const void* obs=d_in[0];
  const void* hx =d_in[1];
  const void* cx =d_in[2];
  const int* acts=(const int*)d_in[3];
  const void* W1 =d_in[4];
  const void* b1 =d_in[5];
  const void* Wih=d_in[6];
  const void* bih=d_in[7];
  const void* Whh=d_in[8];
  const void* bhh=d_in[9];
  const void* Wv =d_in[10];
  const void* bv =d_in[11];
  const void* Wl =d_in[12];
  const void* bl =d_in[13];

  char* w=(char*)d_ws;
  auto alloc=[&](size_t n){ char* p=w; w+=((n+255)&~(size_t)255); return p; };
  int*   flag =(int*)alloc(4);
  int*   cnt  =(int*)alloc(128*4);                 // 16 chunks x 7 barriers
  float* biasg=(float*)alloc((size_t)G_*4);
  float* b1f  =(float*)alloc((size_t)H_*4);
  float* blf  =(float*)alloc(32*4);
  float* cst  =(float*)alloc((size_t)B_*H_*4);     // 1 MB fp32 c
  u16*   hh   =(u16*)alloc((size_t)B_*CH_*H_*2);   // 4 MB fp16 h history
  u16*   xc   =(u16*)alloc((size_t)CR_*H_*2);      // 4 MB fp16 x chunk
  float* xg   =(float*)alloc((size_t)CR_*G_*4);    // 32 MB fp32 xg chunk
  // tiers
  size_t nW=((size_t)H_*F_ + 2*(size_t)G_*H_)*2 + 768;
  bool pathW = ((size_t)(w-(char*)d_ws) + nW) <= ws_size;
  u16 *W1h=0,*Wihp=0,*Whhp=0;
  if(pathW){ W1h=(u16*)alloc((size_t)H_*F_*2); Wihp=(u16*)alloc((size_t)G_*H_*2); Whhp=(u16*)alloc((size_t)G_*H_*2); }
  size_t nXC=(size_t)M_*H_*2 + 256;
  bool pathXC = pathW && (((size_t)(w-(char*)d_ws) + nXC) <= ws_size);
  u16* xcf=0; if(pathXC) xcf=(u16*)alloc((size_t)M_*H_*2);
  size_t nO=(size_t)M_*F_*2 + 256;
  bool pathO = pathXC && (((size_t)(w-(char*)d_ws) + nO) <= ws_size);
  u16* obsh=0; if(pathO) obsh=(u16*)alloc((size_t)M_*F_*2);

  detect<<<1,256,0,stream>>>((const u16*)obs, flag);
  {
    int total=G_+H_+19+128+B_*H_+B_*H_;
    prep<<<(total+255)/256,256,0,stream>>>(bih,bhh,b1,bl,bv,cx,hx, biasg,b1f,blf,cst,hh,cnt, flag);
  }
  if(pathW){
    size_t n=((size_t)H_*F_+2*(size_t)G_*H_)/8;
    convw<<<(int)((n+255)/256),256,0,stream>>>(W1,Wih,Whh, W1h,Wihp,Whhp, flag);
  }
  if(pathO){
    size_t n=(size_t)M_*F_/8;
    convobs<<<(int)((n+255)/256),256,0,stream>>>(obs, obsh, flag);
  }
  if(pathXC){
    gemm128<0,0,0><<<dim3(H_/128, M_/128),256,0,stream>>>(
        pathO?(const void*)obsh:obs, pathW?(const void*)W1h:W1, xcf, b1f, flag,
        F_, F_, F_, H_, 0, pathO?2:-1, pathW?2:-1);
  }

  for(int c=0;c<S_/CH_;c++){
    int t0=c*CH_;
    if(!pathXC){
      gemm128<2,0,0><<<dim3(H_/128, CR_/128),256,0,stream>>>(
          obs, pathW?(const void*)W1h:W1, xc, b1f, flag, F_, F_, F_, H_, t0, -1, pathW?2:-1);
    }
    if(pathXC)
      gemm128<2,0,1><<<dim3(G_/128, CR_/128),256,0,stream>>>(
          xcf, Wihp, xg, biasg, flag, H_, H_, H_, G_, t0, 2, 2);
    else if(pathW)
      gemm128<0,0,1><<<dim3(G_/128, CR_/128),256,0,stream>>>(
          xc, Wihp, xg, biasg, flag, H_, H_, H_, G_, 0, 2, 2);
    else
      gemm128<0,1,1><<<dim3(G_/128, CR_/128),256,0,stream>>>(
          xc, Wih, xg, biasg, flag, H_, H_, H_, G_, 0, 2, -1);

    if(pathW)
      lstm_persist<<<256,512,0,stream>>>(hh, Whhp, xg, cst, cnt+c*8);
    else
      for(int dt=0;dt<CH_;dt++)
        lstm_step<<<dim3(G_/64, B_/64),256,0,stream>>>(hh, (dt+7)&7, dt, Whh, xg, cst, flag);

    heads_chunk<<<dim3(CR_/4),256,0,stream>>>(hh, Wl, Wv, blf, acts, d_out, flag, t0);
  }
}

// Round 8
// 1495.922 us; speedup vs baseline: 4.6103x; 1.2657x over previous
//
#include <hip/hip_runtime.h>

#define B_ 256
#define S_ 128
#define F_ 512
#define H_ 1024
#define A_ 18
#define M_ (B_*S_)      // 32768 output rows (b*S+s)
#define G_ (4*H_)       // 4096 gate cols, permuted unit-major: p = unit*4 + {i,f,g,o}
#define CH_ 16          // timesteps per chunk
#define CR_ (B_*CH_)    // 4096 rows per chunk, row rg = b*CH_ + dt

typedef unsigned short u16;
typedef __attribute__((ext_vector_type(8))) _Float16 f16x8;  // 8 fp16 = 4 VGPR
typedef __attribute__((ext_vector_type(4))) _Float16 f16x4;
typedef __attribute__((ext_vector_type(8))) short   s16x8;
typedef __attribute__((ext_vector_type(4))) float f32x4;
typedef __attribute__((ext_vector_type(4))) unsigned int u32x4;

__device__ __forceinline__ float bf2f(u16 u){
  union{unsigned int i; float f;} v; v.i=((unsigned int)u)<<16; return v.f;
}
__device__ __forceinline__ u16 f2bf(float f){
  unsigned int i=__float_as_uint(f);
  unsigned int r=(i+0x7fffu+((i>>16)&1u))>>16;   // RNE
  return (u16)r;
}
__device__ __forceinline__ u16 f2h(float f){
  _Float16 h=(_Float16)f;
  union{_Float16 h; u16 u;} v; v.h=h; return v.u;
}
// mode-aware scalar load of logical float element i (1: fp32, 0: bf16)
__device__ __forceinline__ float ldf(const void* p, size_t i, int m){
  return m ? ((const float*)p)[i] : bf2f(((const u16*)p)[i]);
}
// load 8 logical floats -> fp16x8. mode 0: bf16 src, 1: fp32 src, 2: raw fp16 src.
__device__ __forceinline__ f16x8 load8_h(const void* base, size_t off, int m){
  f16x8 v;
  if(m==2) return *(const f16x8*)((const u16*)base + off);
  if(m==1){
    const float* f=(const float*)base + off;
    float4 a=*(const float4*)f; float4 b=*(const float4*)(f+4);
    v[0]=(_Float16)a.x; v[1]=(_Float16)a.y; v[2]=(_Float16)a.z; v[3]=(_Float16)a.w;
    v[4]=(_Float16)b.x; v[5]=(_Float16)b.y; v[6]=(_Float16)b.z; v[7]=(_Float16)b.w;
    return v;
  }
  s16x8 w=*(const s16x8*)((const u16*)base + off);
#pragma unroll
  for(int k=0;k<8;k++) v[k]=(_Float16)bf2f((u16)w[k]);
  return v;
}

// ---- coherent (cross-XCD, LLC-routed) 16B load / 2B store: bypass L1+L2 via sc0 sc1.
__device__ __forceinline__ u32x4 load_c16(const void* p){
  u32x4 r;
  asm volatile("global_load_dwordx4 %0, %1, off sc0 sc1" : "=v"(r) : "v"(p));
  return r;
}
__device__ __forceinline__ void store_c2(u16* p, u16 v){
  unsigned int vv=v;
  asm volatile("global_store_short %0, %1, off sc0 sc1" :: "v"(p), "v"(vv) : "memory");
}

// ---- fence-free group barrier (nb participants): own stores drained -> block sync ->
// relaxed agent atomic. hh traffic is sc0/sc1 (LLC-coherent), so no L2 wb/inv needed.
__device__ __forceinline__ void bar_lite(int* c, int nb){
  asm volatile("s_waitcnt vmcnt(0)" ::: "memory");
  __syncthreads();
  if(threadIdx.x==0){
    __hip_atomic_fetch_add(c,1,__ATOMIC_RELAXED,__HIP_MEMORY_SCOPE_AGENT);
    while(__hip_atomic_load(c,__ATOMIC_RELAXED,__HIP_MEMORY_SCOPE_AGENT)<nb)
      __builtin_amdgcn_s_sleep(1);
  }
  __syncthreads();
}

// ---- Stage ROWS x 64 fp16 tile into LDS [ROWS][64], XOR-swizzled 16B chunks (256-thr blocks).
// mode 2: global_load_lds direct (linear dest, inverse-swizzled per-lane src).
// MAP 0: src row = rowoff+r. MAP 1: p=rowoff+r -> (p&3)*H_+(p>>2). MAP 2: p -> (p>>4)*S_+t0+(p&15).
template<int ROWS, int MAP>
__device__ __forceinline__ void stage(const void* base, int mode, int lda, int k0,
                                      int rowoff, int t0, u16* lds, int tid){
  if(mode==2){
    constexpr int NI=(ROWS*8)/256;
    int wv=tid>>6, l=tid&63;
#pragma unroll
    for(int i=0;i<NI;i++){
      int s0=i*256+(wv<<6), s=s0+l;
      int r=s>>3, gc=(s&7)^(r&7);
      int p=rowoff+r, sr;
      if(MAP==0)      sr=p;
      else if(MAP==1) sr=(p&3)*H_+(p>>2);
      else            sr=(p>>4)*S_+t0+(p&15);
      const u16* src=(const u16*)base + (size_t)sr*lda + k0 + gc*8;
      u16* dst=lds + s0*8;             // wave-uniform; HW adds lane*16B
      __builtin_amdgcn_global_load_lds((const __attribute__((address_space(1))) unsigned int*)src,
                                       (__attribute__((address_space(3))) unsigned int*)dst,
                                       16, 0, 0);
    }
  } else {
#pragma unroll
    for(int s0=tid; s0<ROWS*8; s0+=256){
      int r=s0>>3, gc=s0&7, lc=gc^(r&7);
      int p=rowoff+r, sr;
      if(MAP==0)      sr=p;
      else if(MAP==1) sr=(p&3)*H_+(p>>2);
      else            sr=(p>>4)*S_+t0+(p&15);
      f16x8 v=load8_h(base, (size_t)sr*lda + k0 + gc*8, mode);
      *(f16x8*)(lds + r*64 + lc*8)=v;
    }
  }
}

// MFMA 16x16x32 fragment from swizzled LDS tile: lane -> row r0+(l&15), chunk kc+(l>>4), un-XOR.
__device__ __forceinline__ f16x8 frag_ld(const u16* lds, int r0, int kc, int lane){
  int r = r0 + (lane&15);
  int c = (kc + (lane>>4)) ^ (r&7);
  return *(const f16x8*)(lds + r*64 + c*8);
}

// ---- 128x128-tile GEMM: C = A * B^T + biasf. amode/bmode: <0 -> *flag, else literal.
// OUTMODE 0: relu+fp16. 1: fp32. 2: fp16 (no relu).
template<int AMAP, int BMAP, int OUTMODE>
__global__ __launch_bounds__(256,3) void gemm128(const void* A, const void* Bt, void* C,
    const float* __restrict__ biasf, const int* __restrict__ flag,
    int K, int lda, int ldb, int ldc, int t0, int amode, int bmode){
  int m=*flag;
  int am = amode<0 ? m : amode;
  int bm_ = bmode<0 ? m : bmode;
  __shared__ u16 As[128*64];
  __shared__ u16 Bs[128*64];
  int tid=threadIdx.x, lane=tid&63, w=tid>>6;
  int bm=blockIdx.y*128, bn=blockIdx.x*128;
  int wm=(w&1)*64, wn=(w>>1)*64;
  f32x4 acc[4][4];
#pragma unroll
  for(int i=0;i<4;i++)
#pragma unroll
    for(int j=0;j<4;j++) acc[i][j]=(f32x4)(0.f);
  for(int k0=0;k0<K;k0+=64){
    stage<128,AMAP>(A , am,  lda, k0, bm, t0, As, tid);
    stage<128,BMAP>(Bt, bm_, ldb, k0, bn, t0, Bs, tid);
    __syncthreads();
#pragma unroll
    for(int kk=0;kk<2;kk++){
      f16x8 af[4], bq[4];
#pragma unroll
      for(int i=0;i<4;i++) af[i]=frag_ld(As, wm+i*16, kk*4, lane);
#pragma unroll
      for(int j=0;j<4;j++) bq[j]=frag_ld(Bs, wn+j*16, kk*4, lane);
#pragma unroll
      for(int i=0;i<4;i++)
#pragma unroll
        for(int j=0;j<4;j++)
          acc[i][j]=__builtin_amdgcn_mfma_f32_16x16x32_f16(af[i],bq[j],acc[i][j],0,0,0);
    }
    __syncthreads();
  }
  int rl=lane>>4, cl=lane&15;
#pragma unroll
  for(int j=0;j<4;j++){
    int col=bn+wn+j*16+cl;
    float bb=biasf[col];
#pragma unroll
    for(int i=0;i<4;i++){
#pragma unroll
      for(int r=0;r<4;r++){
        int row=bm+wm+i*16+rl*4+r;
        float v=acc[i][j][r]+bb;
        if(OUTMODE==0){ v=fmaxf(v,0.f); ((u16*)C)[(size_t)row*ldc+col]=f2h(v); }
        else if(OUTMODE==2){ ((u16*)C)[(size_t)row*ldc+col]=f2h(v); }
        else { ((float*)C)[(size_t)row*ldc+col]=v; }
      }
    }
  }
}

// ---- persistent chunk-LSTM v4: Whh PINNED in VGPRs, group-local barriers, fp16 xg prefetch.
// Grid 256, 512 threads. xcd=blockIdx&7, slot=blockIdx>>3.
// Batch group grp=xcd>>1 (one XCD pair); bm=grp*64. Col group: bn=((xcd&1)*32+slot)*64.
// Wave w: mh=w&1 (32-row grp), ch=(w>>1)&1 (32-col grp), q=w>>2 (512-K half).
__global__ __launch_bounds__(512,2) void lstm_persist(u16* __restrict__ hh,
        const u16* __restrict__ Whhp, const u16* __restrict__ xgp, int ldseq,
        float* __restrict__ cst, int* __restrict__ cntc){
  __shared__ u16 As[16*4096];     // 128 KB: 16 k-tiles [64][64], XOR-swizzled
  __shared__ float gs[64*68];     // 17 KB padded
  int tid=threadIdx.x, lane=tid&63, w=tid>>6;
  int mh=w&1, ch=(w>>1)&1, q=w>>2;
  int xcd=blockIdx.x&7, slot=blockIdx.x>>3;
  int grp=xcd>>1;
  int bm=grp*64, bn=((xcd&1)*32+slot)*64;

  // Whh slice -> 32 u32x4 VGPR tuples (128 VGPR), PINNED against rematerialization.
  u32x4 bw[32];
#pragma unroll
  for(int c2=0;c2<2;c2++){
#pragma unroll
    for(int t=0;t<16;t++){
      int p = bn + ch*32 + c2*16 + (lane&15);
      int k = q*512 + t*32 + (lane>>4)*8;
      bw[c2*16+t]=*(const u32x4*)(Whhp + (size_t)p*H_ + k);
    }
  }
#pragma unroll
  for(int i=0;i<32;i++) asm volatile("" : "+v"(bw[i]));

  // c-state in regs; thread owns cells (rl0,u0) and (rl1,u0).
  int rl0=tid>>4, rl1=(tid+512)>>4, u0=tid&15;
  int gu=(bn>>2)+u0;
  float c0=cst[(size_t)(bm+rl0)*H_+gu];
  float c1=cst[(size_t)(bm+rl1)*H_+gu];
  // staging assignment
  int sr=tid>>3, sc=tid&7, slc=sc^(sr&7);

  for(int dt=0;dt<CH_;dt++){
    // xg prefetch (fp16, cached loads) — independent of h, issued BEFORE the barrier
    f16x4 xv0=*(const f16x4*)(xgp + ((size_t)(bm+rl0)*ldseq+dt)*G_ + bn + u0*4);
    f16x4 xv1=*(const f16x4*)(xgp + ((size_t)(bm+rl1)*ldseq+dt)*G_ + bn + u0*4);
    if(dt) bar_lite(cntc+(dt-1)*4+grp, 64);
    // stage h_prev[64][1024]: 16 coherent 16B loads -> regs -> LDS (swizzled dest)
    {
      int slotPrev=(dt+CH_-1)&(CH_-1);
      const u16* hsrc = hh + ((size_t)(bm+sr)*CH_+slotPrev)*H_ + sc*8;
      u32x4 tmp[16];
#pragma unroll
      for(int kt=0;kt<16;kt++) tmp[kt]=load_c16(hsrc + kt*64);
      asm volatile("s_waitcnt vmcnt(0)" ::: "memory");
#pragma unroll
      for(int kt=0;kt<16;kt++)
        *(u32x4*)(As + kt*4096 + sr*64 + slc*8)=tmp[kt];
    }
    __syncthreads();
    // MFMA over wave's K-half: 64 MFMA
    f32x4 acc[2][2];
#pragma unroll
    for(int i=0;i<2;i++){ acc[i][0]=(f32x4)(0.f); acc[i][1]=(f32x4)(0.f); }
#pragma unroll
    for(int t=0;t<16;t++){
      int kt=q*8+(t>>1), kk=t&1;
      f16x8 af[2];
#pragma unroll
      for(int i=0;i<2;i++) af[i]=frag_ld(As+kt*4096, mh*32+i*16, kk*4, lane);
      f16x8 b0=__builtin_bit_cast(f16x8, bw[t]);
      f16x8 b1=__builtin_bit_cast(f16x8, bw[16+t]);
#pragma unroll
      for(int i=0;i<2;i++){
        acc[i][0]=__builtin_amdgcn_mfma_f32_16x16x32_f16(af[i],b0,acc[i][0],0,0,0);
        acc[i][1]=__builtin_amdgcn_mfma_f32_16x16x32_f16(af[i],b1,acc[i][1],0,0,0);
      }
    }
    // 2-phase K reduction into gs
    if(q==0){
#pragma unroll
      for(int i=0;i<2;i++)
#pragma unroll
        for(int c2=0;c2<2;c2++)
#pragma unroll
          for(int r=0;r<4;r++)
            gs[(mh*32+i*16+(lane>>4)*4+r)*68 + ch*32+c2*16+(lane&15)]=acc[i][c2][r];
    }
    __syncthreads();
    if(q==1){
#pragma unroll
      for(int i=0;i<2;i++)
#pragma unroll
        for(int c2=0;c2<2;c2++)
#pragma unroll
          for(int r=0;r<4;r++)
            gs[(mh*32+i*16+(lane>>4)*4+r)*68 + ch*32+c2*16+(lane&15)]+=acc[i][c2][r];
    }
    __syncthreads();
    // elementwise (2 cells/thread); coherent h store
    {
      float4 gv=*(const float4*)&gs[rl0*68+u0*4];
      float ii=1.f/(1.f+__expf(-(gv.x+(float)xv0[0])));
      float ff=1.f/(1.f+__expf(-(gv.y+(float)xv0[1])));
      float gg=1.f-2.f/(__expf(2.f*(gv.z+(float)xv0[2]))+1.f);
      float oo=1.f/(1.f+__expf(-(gv.w+(float)xv0[3])));
      c0=ff*c0+ii*gg;
      float th=1.f-2.f/(__expf(2.f*c0)+1.f);
      store_c2(hh + (size_t)(bm+rl0)*(CH_*H_) + dt*H_ + gu, f2h(oo*th));
    }
    {
      float4 gv=*(const float4*)&gs[rl1*68+u0*4];
      float ii=1.f/(1.f+__expf(-(gv.x+(float)xv1[0])));
      float ff=1.f/(1.f+__expf(-(gv.y+(float)xv1[1])));
      float gg=1.f-2.f/(__expf(2.f*(gv.z+(float)xv1[2]))+1.f);
      float oo=1.f/(1.f+__expf(-(gv.w+(float)xv1[3])));
      c1=ff*c1+ii*gg;
      float th=1.f-2.f/(__expf(2.f*c1)+1.f);
      store_c2(hh + (size_t)(bm+rl1)*(CH_*H_) + dt*H_ + gu, f2h(oo*th));
    }
  }
  cst[(size_t)(bm+rl0)*H_+gu]=c0;
  cst[(size_t)(bm+rl1)*H_+gu]=c1;
}

// ---- fallback per-step LSTM (low-ws tier): gates = xg(fp16) + h_prev @ Whh(perm)^T.
__global__ __launch_bounds__(256,2) void lstm_step(u16* __restrict__ hh, int slotPrev, int dt,
        const void* __restrict__ Whh, const u16* __restrict__ xg,
        float* __restrict__ cst, const int* __restrict__ flag){
  int m=*flag;
  __shared__ u16 As[64*64];
  __shared__ u16 Bs[64*64];
  __shared__ float gs[64*64];
  int tid=threadIdx.x, lane=tid&63, w=tid>>6;
  int bm=blockIdx.y*64, bn=blockIdx.x*64;
  int wm=(w&1)*32, wn=(w>>1)*32;
  f32x4 acc[2][2];
#pragma unroll
  for(int i=0;i<2;i++)
#pragma unroll
    for(int j=0;j<2;j++) acc[i][j]=(f32x4)(0.f);
  for(int k0=0;k0<H_;k0+=64){
    stage<64,0>(hh + slotPrev*H_, 2, CH_*H_, k0, bm, 0, As, tid);
    stage<64,1>(Whh,              m, H_,     k0, bn, 0, Bs, tid);
    __syncthreads();
#pragma unroll
    for(int kk=0;kk<2;kk++){
      f16x8 af[2], bq[2];
#pragma unroll
      for(int i=0;i<2;i++) af[i]=frag_ld(As, wm+i*16, kk*4, lane);
#pragma unroll
      for(int j=0;j<2;j++) bq[j]=frag_ld(Bs, wn+j*16, kk*4, lane);
#pragma unroll
      for(int i=0;i<2;i++)
#pragma unroll
        for(int j=0;j<2;j++)
          acc[i][j]=__builtin_amdgcn_mfma_f32_16x16x32_f16(af[i],bq[j],acc[i][j],0,0,0);
    }
    __syncthreads();
  }
  int rl=lane>>4, cl=lane&15;
#pragma unroll
  for(int j=0;j<2;j++){
    int coll=wn+j*16+cl;
#pragma unroll
    for(int i=0;i<2;i++){
#pragma unroll
      for(int r=0;r<4;r++){
        int rowl=wm+i*16+rl*4+r;
        float xv=(float)((const _Float16*)xg)[((size_t)(bm+rowl)*CH_+dt)*G_ + bn+coll];
        gs[rowl*64+coll]=acc[i][j][r] + xv;
      }
    }
  }
  __syncthreads();
#pragma unroll
  for(int p=0;p<4;p++){
    int idx=p*256+tid;
    int rowl=idx>>4, u=idx&15;
    float4 gv = *(const float4*)&gs[rowl*64+u*4];
    float ii=1.f/(1.f+__expf(-gv.x));
    float ff=1.f/(1.f+__expf(-gv.y));
    float gg=1.f-2.f/(__expf(2.f*gv.z)+1.f);
    float oo=1.f/(1.f+__expf(-gv.w));
    int gb=bm+rowl;
    int gu=(bn>>2)+u;
    size_t ci=(size_t)gb*H_+gu;
    float cn=ff*cst[ci]+ii*gg;
    cst[ci]=cn;
    float th=1.f-2.f/(__expf(2.f*cn)+1.f);
    hh[(size_t)gb*(CH_*H_) + dt*H_ + gu]=f2h(oo*th);
  }
}

// ---- heads for one chunk: wave per row rg=b*CH_+dt; output gw=b*S+t0+dt.
__global__ __launch_bounds__(256,2) void heads_chunk(const u16* __restrict__ hh,
      const void* __restrict__ Wl, const void* __restrict__ Wv,
      const float* __restrict__ blf, const int* __restrict__ acts,
      void* __restrict__ out, const int* __restrict__ flag, int t0){
  int m=*flag;
  int rg = blockIdx.x*4 + (threadIdx.x>>6);
  int lane = threadIdx.x & 63;
  const u16* h = hh + (size_t)rg*H_;               // fp16
  f16x8 h0=*(const f16x8*)(h + lane*16), h1=*(const f16x8*)(h + lane*16 + 8);
  float hv[16];
#pragma unroll
  for(int k=0;k<8;k++){ hv[k]=(float)h0[k]; hv[8+k]=(float)h1[k]; }
  float dots[19];
#pragma unroll
  for(int j=0;j<19;j++){
    const void* wrow = (j<18) ? Wl : Wv;
    size_t roff = (j<18) ? (size_t)j*H_ : 0;
    float wv_[16];
    if(m){
      const float* f=(const float*)wrow + roff + lane*16;
      float4 a=*(const float4*)f, b=*(const float4*)(f+4), c=*(const float4*)(f+8), d=*(const float4*)(f+12);
      wv_[0]=a.x;wv_[1]=a.y;wv_[2]=a.z;wv_[3]=a.w; wv_[4]=b.x;wv_[5]=b.y;wv_[6]=b.z;wv_[7]=b.w;
      wv_[8]=c.x;wv_[9]=c.y;wv_[10]=c.z;wv_[11]=c.w; wv_[12]=d.x;wv_[13]=d.y;wv_[14]=d.z;wv_[15]=d.w;
    } else {
      const u16* ub=(const u16*)wrow + roff + lane*16;
      s16x8 w0=*(const s16x8*)ub, w1=*(const s16x8*)(ub+8);
#pragma unroll
      for(int k=0;k<8;k++){ wv_[k]=bf2f((u16)w0[k]); wv_[8+k]=bf2f((u16)w1[k]); }
    }
    float d=0.f;
#pragma unroll
    for(int k=0;k<16;k++) d += hv[k]*wv_[k];
#pragma unroll
    for(int mm=1;mm<64;mm<<=1) d += __shfl_xor(d, mm, 64);
    dots[j]=d;
  }
  float lg[18];
#pragma unroll
  for(int j=0;j<18;j++) lg[j]=dots[j]+blf[j];
  float value=dots[18]+blf[18];
  float mx=lg[0];
#pragma unroll
  for(int j=1;j<18;j++) mx=fmaxf(mx,lg[j]);
  float se=0.f, s1=0.f;
#pragma unroll
  for(int j=0;j<18;j++){ float e=__expf(lg[j]-mx); se+=e; s1+=e*(lg[j]-mx); }
  float lse=__logf(se);
  int b=rg>>4, dt=rg&(CH_-1);
  int gw = b*S_ + t0 + dt;
  int a=acts[gw];
  float la=0.f;
#pragma unroll
  for(int j=0;j<18;j++) la = (j==a) ? lg[j] : la;
  float lp=la-mx-lse;
  float ent=lse - s1/se;
  if(lane==0){
    if(m){
      ((float*)out)[gw]=lp; ((float*)out)[M_+gw]=ent; ((float*)out)[2*M_+gw]=value;
    } else {
      ((u16*)out)[gw]=f2bf(lp); ((u16*)out)[M_+gw]=f2bf(ent); ((u16*)out)[2*M_+gw]=f2bf(value);
    }
  }
}

// ---- dtype detect
__global__ void detect(const u16* __restrict__ obs_w, int* __restrict__ flag){
  __shared__ float red[256];
  float mx=0.f;
  for(int i=threadIdx.x;i<4096;i+=256) mx=fmaxf(mx,fabsf(bf2f(obs_w[i])));
  red[threadIdx.x]=mx; __syncthreads();
  for(int s=128;s>0;s>>=1){
    if(threadIdx.x<s) red[threadIdx.x]=fmaxf(red[threadIdx.x],red[threadIdx.x+s]);
    __syncthreads();
  }
  if(threadIdx.x==0) *flag=(red[0]>1e4f)?1:0;
}

// ---- prep: biases, c state, h seed (fp16, slot CH_-1), zero barrier counters.
__global__ void prep(const void* bih, const void* bhh, const void* b1, const void* bl, const void* bv,
                     const void* cx, const void* hx,
                     float* biasg, float* b1f, float* blf, float* cst, u16* hh,
                     int* cnt, const int* __restrict__ flag){
  int m=*flag;
  size_t i=(size_t)blockIdx.x*256+threadIdx.x;
  if(i<G_){ size_t rm=(i&3)*H_+(i>>2); biasg[i]=ldf(bih,rm,m)+ldf(bhh,rm,m); return; }
  i-=G_;
  if(i<H_){ b1f[i]=ldf(b1,i,m); return; }
  i-=H_;
  if(i<19){ blf[i]=(i<18)?ldf(bl,i,m):ldf(bv,0,m); return; }
  i-=19;
  if(i<512){ cnt[i]=0; return; }
  i-=512;
  if(i<(size_t)B_*H_){ cst[i]=ldf(cx,i,m); return; }
  i-=(size_t)B_*H_;
  if(i<(size_t)B_*H_){
    size_t b=i>>10, k=i&1023;
    hh[b*(CH_*H_) + (CH_-1)*H_ + k]=f2h(ldf(hx,i,m));
  }
}

// ---- weight pre-conversion to fp16 (exact from bf16), gate-permuted for Wih/Whh.
__global__ void convw(const void* W1, const void* Wih, const void* Whh,
                      u16* W1h, u16* Wihp, u16* Whhp, const int* __restrict__ flag){
  int m=*flag;
  size_t i=((size_t)blockIdx.x*256+threadIdx.x)*8;
  const size_t n1=(size_t)H_*F_, n2=(size_t)G_*H_;
  if(i<n1){ *(f16x8*)(W1h+i)=load8_h(W1,i,m); return; }
  i-=n1;
  if(i<n2){ size_t p=i>>10, c=i&1023; size_t sr=(p&3)*H_+(p>>2);
            *(f16x8*)(Wihp+i)=load8_h(Wih, sr*H_+c, m); return; }
  i-=n2;
  if(i<n2){ size_t p=i>>10, c=i&1023; size_t sr=(p&3)*H_+(p>>2);
            *(f16x8*)(Whhp+i)=load8_h(Whh, sr*H_+c, m); return; }
}
__global__ void convobs(const void* obs, u16* obsh, const int* __restrict__ flag){
  int m=*flag;
  size_t i=((size_t)blockIdx.x*256+threadIdx.x)*8;
  if(i<(size_t)M_*F_) *(f16x8*)(obsh+i)=load8_h(obs,i,m);
}

extern "C" void kernel_launch(void* const* d_in, const int* in_sizes, int n_in,
                              void* d_out, int out_size, void* d_ws, size_t ws_size,
                              hipStream_t stream){
  const void* obs=d_in[0];
  const void* hx =d_in[1];
  const void* cx =d_in[2];
  const int* acts=(const int*)d_in[3];
  const void* W1 =d_in[4];
  const void* b1 =d_in[5];
  const void* Wih=d_in[6];
  const void* bih=d_in[7];
  const void* Whh=d_in[8];
  const void* bhh=d_in[9];
  const void* Wv =d_in[10];
  const void* bv =d_in[11];
  const void* Wl =d_in[12];
  const void* bl =d_in[13];

  char* w=(char*)d_ws;
  auto alloc=[&](size_t n){ char* p=w; w+=((n+255)&~(size_t)255); return p; };
  int*   flag =(int*)alloc(4);
  int*   cnt  =(int*)alloc(512*4);                 // 8 chunks x 15 steps x 4 groups
  float* biasg=(float*)alloc((size_t)G_*4);
  float* b1f  =(float*)alloc((size_t)H_*4);
  float* blf  =(float*)alloc(32*4);
  float* cst  =(float*)alloc((size_t)B_*H_*4);     // 1 MB fp32 c
  u16*   hh   =(u16*)alloc((size_t)B_*CH_*H_*2);   // 8 MB fp16 h history [B][16][H]
  u16*   xc   =(u16*)alloc((size_t)CR_*H_*2);      // 8 MB fp16 x chunk
  u16*   xg   =(u16*)alloc((size_t)CR_*G_*2);      // 32 MB fp16 xg chunk
  // tiers
  size_t nW=((size_t)H_*F_ + 2*(size_t)G_*H_)*2 + 768;
  bool pathW = ((size_t)(w-(char*)d_ws) + nW) <= ws_size;
  u16 *W1h=0,*Wihp=0,*Whhp=0;
  if(pathW){ W1h=(u16*)alloc((size_t)H_*F_*2); Wihp=(u16*)alloc((size_t)G_*H_*2); Whhp=(u16*)alloc((size_t)G_*H_*2); }
  size_t nXC=(size_t)M_*H_*2 + 256;
  bool pathXC = pathW && (((size_t)(w-(char*)d_ws) + nXC) <= ws_size);
  u16* xcf=0; if(pathXC) xcf=(u16*)alloc((size_t)M_*H_*2);
  size_t nO=(size_t)M_*F_*2 + 256;
  bool pathO = pathXC && (((size_t)(w-(char*)d_ws) + nO) <= ws_size);
  u16* obsh=0; if(pathO) obsh=(u16*)alloc((size_t)M_*F_*2);

  detect<<<1,256,0,stream>>>((const u16*)obs, flag);
  {
    int total=G_+H_+19+512+B_*H_+B_*H_;
    prep<<<(total+255)/256,256,0,stream>>>(bih,bhh,b1,bl,bv,cx,hx, biasg,b1f,blf,cst,hh,cnt, flag);
  }
  if(pathW){
    size_t n=((size_t)H_*F_+2*(size_t)G_*H_)/8;
    convw<<<(int)((n+255)/256),256,0,stream>>>(W1,Wih,Whh, W1h,Wihp,Whhp, flag);
  }
  if(pathO){
    size_t n=(size_t)M_*F_/8;
    convobs<<<(int)((n+255)/256),256,0,stream>>>(obs, obsh, flag);
  }
  if(pathXC){
    gemm128<0,0,0><<<dim3(H_/128, M_/128),256,0,stream>>>(
        pathO?(const void*)obsh:obs, pathW?(const void*)W1h:W1, xcf, b1f, flag,
        F_, F_, F_, H_, 0, pathO?2:-1, pathW?2:-1);
  }

  for(int c=0;c<S_/CH_;c++){
    int t0=c*CH_;
    if(!pathXC){
      gemm128<2,0,0><<<dim3(H_/128, CR_/128),256,0,stream>>>(
          obs, pathW?(const void*)W1h:W1, xc, b1f, flag, F_, F_, F_, H_, t0, -1, pathW?2:-1);
    }
    if(pathXC)
      gemm128<2,0,2><<<dim3(G_/128, CR_/128),256,0,stream>>>(
          xcf, Wihp, xg, biasg, flag, H_, H_, H_, G_, t0, 2, 2);
    else if(pathW)
      gemm128<0,0,2><<<dim3(G_/128, CR_/128),256,0,stream>>>(
          xc, Wihp, xg, biasg, flag, H_, H_, H_, G_, 0, 2, 2);
    else
      gemm128<0,1,2><<<dim3(G_/128, CR_/128),256,0,stream>>>(
          xc, Wih, xg, biasg, flag, H_, H_, H_, G_, 0, 2, -1);

    if(pathW)
      lstm_persist<<<256,512,0,stream>>>(hh, Whhp, xg, CH_, cst, cnt+c*64);
    else
      for(int dt=0;dt<CH_;dt++)
        lstm_step<<<dim3(G_/64, B_/64),256,0,stream>>>(hh, (dt+CH_-1)&(CH_-1), dt, Whh, xg, cst, flag);

    heads_chunk<<<dim3(CR_/4),256,0,stream>>>(hh, Wl, Wv, blf, acts, d_out, flag, t0);
  }
}

// Round 9
// 1365.414 us; speedup vs baseline: 5.0510x; 1.0956x over previous
//
#include <hip/hip_runtime.h>

#define B_ 256
#define S_ 128
#define F_ 512
#define H_ 1024
#define A_ 18
#define M_ (B_*S_)      // 32768 output rows (b*S+s)
#define G_ (4*H_)       // 4096 gate cols, permuted unit-major: p = unit*4 + {i,f,g,o}
#define CH_ 16          // timesteps per chunk
#define CR_ (B_*CH_)    // 4096 rows per chunk, row rg = b*CH_ + dt

typedef unsigned short u16;
typedef __attribute__((ext_vector_type(8))) _Float16 f16x8;  // 8 fp16 = 4 VGPR
typedef __attribute__((ext_vector_type(4))) _Float16 f16x4;
typedef __attribute__((ext_vector_type(8))) short   s16x8;
typedef __attribute__((ext_vector_type(4))) float f32x4;
typedef __attribute__((ext_vector_type(4))) unsigned int u32x4;

__device__ __forceinline__ float bf2f(u16 u){
  union{unsigned int i; float f;} v; v.i=((unsigned int)u)<<16; return v.f;
}
__device__ __forceinline__ u16 f2bf(float f){
  unsigned int i=__float_as_uint(f);
  unsigned int r=(i+0x7fffu+((i>>16)&1u))>>16;   // RNE
  return (u16)r;
}
__device__ __forceinline__ u16 f2h(float f){
  _Float16 h=(_Float16)f;
  union{_Float16 h; u16 u;} v; v.h=h; return v.u;
}
// mode-aware scalar load of logical float element i (1: fp32, 0: bf16)
__device__ __forceinline__ float ldf(const void* p, size_t i, int m){
  return m ? ((const float*)p)[i] : bf2f(((const u16*)p)[i]);
}
// load 8 logical floats -> fp16x8. mode 0: bf16 src, 1: fp32 src, 2: raw fp16 src.
__device__ __forceinline__ f16x8 load8_h(const void* base, size_t off, int m){
  f16x8 v;
  if(m==2) return *(const f16x8*)((const u16*)base + off);
  if(m==1){
    const float* f=(const float*)base + off;
    float4 a=*(const float4*)f; float4 b=*(const float4*)(f+4);
    v[0]=(_Float16)a.x; v[1]=(_Float16)a.y; v[2]=(_Float16)a.z; v[3]=(_Float16)a.w;
    v[4]=(_Float16)b.x; v[5]=(_Float16)b.y; v[6]=(_Float16)b.z; v[7]=(_Float16)b.w;
    return v;
  }
  s16x8 w=*(const s16x8*)((const u16*)base + off);
#pragma unroll
  for(int k=0;k<8;k++) v[k]=(_Float16)bf2f((u16)w[k]);
  return v;
}

// ---- coherent (cross-XCD, LLC-routed) accesses: bypass L1+L2 via sc0 sc1.
__device__ __forceinline__ u32x4 load_c16(const void* p){
  u32x4 r;
  asm volatile("global_load_dwordx4 %0, %1, off sc0 sc1" : "=v"(r) : "v"(p));
  return r;
}
__device__ __forceinline__ void store_c2(u16* p, u16 v){
  unsigned int vv=v;
  asm volatile("global_store_short %0, %1, off sc0 sc1" :: "v"(p), "v"(vv) : "memory");
}
__device__ __forceinline__ int load_c4(const int* p){
  int r;
  asm volatile("global_load_dword %0, %1, off sc0 sc1" : "=v"(r) : "v"(p));
  return r;
}
__device__ __forceinline__ void store_c4(int* p, int v){
  asm volatile("global_store_dword %0, %1, off sc0 sc1" :: "v"(p), "v"(v) : "memory");
}

// ---- store-flag group barrier (64 blocks): arrival = own-flag store (monotonic target),
// departure = wave-0 parallel poll of all 64 flags (one LLC round trip per probe).
__device__ __forceinline__ void bar_flags(int* flags, int target, int gi, int lane, int w){
  asm volatile("s_waitcnt vmcnt(0)" ::: "memory");   // own h stores at LLC
  __syncthreads();
  if(w==0){
    if(lane==0) store_c4(flags+gi, target);
    while(true){
      int v=load_c4(flags+lane);
      asm volatile("s_waitcnt vmcnt(0)" ::: "memory");
      if(__all(v>=target)) break;
      __builtin_amdgcn_s_sleep(1);
    }
  }
  __syncthreads();
}

// ---- Stage ROWS x 64 fp16 tile into LDS [ROWS][64], XOR-swizzled 16B chunks (256-thr blocks).
// mode 2: global_load_lds direct (linear dest, inverse-swizzled per-lane src).
// MAP 0: src row = rowoff+r. MAP 1: p=rowoff+r -> (p&3)*H_+(p>>2). MAP 2: p -> (p>>4)*S_+t0+(p&15).
template<int ROWS, int MAP>
__device__ __forceinline__ void stage(const void* base, int mode, int lda, int k0,
                                      int rowoff, int t0, u16* lds, int tid){
  if(mode==2){
    constexpr int NI=(ROWS*8)/256;
    int wv=tid>>6, l=tid&63;
#pragma unroll
    for(int i=0;i<NI;i++){
      int s0=i*256+(wv<<6), s=s0+l;
      int r=s>>3, gc=(s&7)^(r&7);
      int p=rowoff+r, sr;
      if(MAP==0)      sr=p;
      else if(MAP==1) sr=(p&3)*H_+(p>>2);
      else            sr=(p>>4)*S_+t0+(p&15);
      const u16* src=(const u16*)base + (size_t)sr*lda + k0 + gc*8;
      u16* dst=lds + s0*8;             // wave-uniform; HW adds lane*16B
      __builtin_amdgcn_global_load_lds((const __attribute__((address_space(1))) unsigned int*)src,
                                       (__attribute__((address_space(3))) unsigned int*)dst,
                                       16, 0, 0);
    }
  } else {
#pragma unroll
    for(int s0=tid; s0<ROWS*8; s0+=256){
      int r=s0>>3, gc=s0&7, lc=gc^(r&7);
      int p=rowoff+r, sr;
      if(MAP==0)      sr=p;
      else if(MAP==1) sr=(p&3)*H_+(p>>2);
      else            sr=(p>>4)*S_+t0+(p&15);
      f16x8 v=load8_h(base, (size_t)sr*lda + k0 + gc*8, mode);
      *(f16x8*)(lds + r*64 + lc*8)=v;
    }
  }
}

// MFMA 16x16x32 fragment from swizzled LDS tile: lane -> row r0+(l&15), chunk kc+(l>>4), un-XOR.
__device__ __forceinline__ f16x8 frag_ld(const u16* lds, int r0, int kc, int lane){
  int r = r0 + (lane&15);
  int c = (kc + (lane>>4)) ^ (r&7);
  return *(const f16x8*)(lds + r*64 + c*8);
}

// ---- 128x128-tile GEMM: C = A * B^T + biasf. amode/bmode: <0 -> *flag, else literal.
// OUTMODE 0: relu+fp16. 1: fp32. 2: fp16 (no relu).
template<int AMAP, int BMAP, int OUTMODE>
__global__ __launch_bounds__(256,3) void gemm128(const void* A, const void* Bt, void* C,
    const float* __restrict__ biasf, const int* __restrict__ flag,
    int K, int lda, int ldb, int ldc, int t0, int amode, int bmode){
  int m=*flag;
  int am = amode<0 ? m : amode;
  int bm_ = bmode<0 ? m : bmode;
  __shared__ u16 As[128*64];
  __shared__ u16 Bs[128*64];
  int tid=threadIdx.x, lane=tid&63, w=tid>>6;
  int bm=blockIdx.y*128, bn=blockIdx.x*128;
  int wm=(w&1)*64, wn=(w>>1)*64;
  f32x4 acc[4][4];
#pragma unroll
  for(int i=0;i<4;i++)
#pragma unroll
    for(int j=0;j<4;j++) acc[i][j]=(f32x4)(0.f);
  for(int k0=0;k0<K;k0+=64){
    stage<128,AMAP>(A , am,  lda, k0, bm, t0, As, tid);
    stage<128,BMAP>(Bt, bm_, ldb, k0, bn, t0, Bs, tid);
    __syncthreads();
#pragma unroll
    for(int kk=0;kk<2;kk++){
      f16x8 af[4], bq[4];
#pragma unroll
      for(int i=0;i<4;i++) af[i]=frag_ld(As, wm+i*16, kk*4, lane);
#pragma unroll
      for(int j=0;j<4;j++) bq[j]=frag_ld(Bs, wn+j*16, kk*4, lane);
#pragma unroll
      for(int i=0;i<4;i++)
#pragma unroll
        for(int j=0;j<4;j++)
          acc[i][j]=__builtin_amdgcn_mfma_f32_16x16x32_f16(af[i],bq[j],acc[i][j],0,0,0);
    }
    __syncthreads();
  }
  int rl=lane>>4, cl=lane&15;
#pragma unroll
  for(int j=0;j<4;j++){
    int col=bn+wn+j*16+cl;
    float bb=biasf[col];
#pragma unroll
    for(int i=0;i<4;i++){
#pragma unroll
      for(int r=0;r<4;r++){
        int row=bm+wm+i*16+rl*4+r;
        float v=acc[i][j][r]+bb;
        if(OUTMODE==0){ v=fmaxf(v,0.f); ((u16*)C)[(size_t)row*ldc+col]=f2h(v); }
        else if(OUTMODE==2){ ((u16*)C)[(size_t)row*ldc+col]=f2h(v); }
        else { ((float*)C)[(size_t)row*ldc+col]=v; }
      }
    }
  }
}

// ---- persistent chunk-LSTM v5: full-K waves (no K-reduction), store-flag barrier,
// Whh pinned in AGPRs. Grid 256, 512 threads. xcd=blockIdx&7, slot=blockIdx>>3.
// Batch group grp=xcd>>1; bm=grp*64. Cols: bn=((xcd&1)*32+slot)*64; gi=(xcd&1)*32+slot.
// Wave w: mh=w&1 (32-row grp), cn=w>>1 (16-col tile), K full (1024).
__global__ __launch_bounds__(512,2) void lstm_persist(u16* __restrict__ hh,
        const u16* __restrict__ Whhp, const u16* __restrict__ xgp,
        float* __restrict__ cst, int* __restrict__ cntc, int tbase){
  __shared__ u16 As[16*4096];     // 128 KB: 16 k-tiles [64][64], XOR-swizzled
  __shared__ float gs[64*72];     // 18 KB, stride 72 (2-way banks max)
  int tid=threadIdx.x, lane=tid&63, w=tid>>6;
  int mh=w&1, cn=w>>1;
  int xcd=blockIdx.x&7, slot=blockIdx.x>>3;
  int grp=xcd>>1, gi=(xcd&1)*32+slot;
  int bm=grp*64, bn=gi*64;
  int* flags = cntc + grp*64;

  // Whh slice -> 32 f16x8, pinned in AGPRs (128 regs; survives the step loop).
  f16x8 bw[32];
#pragma unroll
  for(int t=0;t<32;t++){
    int p = bn + cn*16 + (lane&15);
    int k = t*32 + (lane>>4)*8;
    bw[t]=*(const f16x8*)(Whhp + (size_t)p*H_ + k);
  }
#pragma unroll
  for(int t=0;t<32;t++) asm volatile("" : "+a"(bw[t]));

  // c-state in regs; thread owns cells (rl0,u0) and (rl1,u0).
  int rl0=tid>>4, rl1=(tid+512)>>4, u0=tid&15;
  int gu=(bn>>2)+u0;
  float c0=cst[(size_t)(bm+rl0)*H_+gu];
  float c1=cst[(size_t)(bm+rl1)*H_+gu];
  // staging assignment
  int sr=tid>>3, sc=tid&7, slc=sc^(sr&7);

  for(int dt=0;dt<CH_;dt++){
    // xg prefetch (fp16, cached) — independent of h, issued BEFORE the barrier
    f16x4 xv0=*(const f16x4*)(xgp + ((size_t)(bm+rl0)*CH_+dt)*G_ + bn + u0*4);
    f16x4 xv1=*(const f16x4*)(xgp + ((size_t)(bm+rl1)*CH_+dt)*G_ + bn + u0*4);
    if(dt) bar_flags(flags, tbase+dt, gi, lane, w);
    // stage h_prev[64][1024]: 16 coherent 16B loads -> regs -> LDS (swizzled dest)
    {
      int slotPrev=(dt+CH_-1)&(CH_-1);
      const u16* hsrc = hh + ((size_t)(bm+sr)*CH_+slotPrev)*H_ + sc*8;
      u32x4 tmp[16];
#pragma unroll
      for(int kt=0;kt<16;kt++) tmp[kt]=load_c16(hsrc + kt*64);
      asm volatile("s_waitcnt vmcnt(0)" ::: "memory");
#pragma unroll
      for(int kt=0;kt<16;kt++)
        *(u32x4*)(As + kt*4096 + sr*64 + slc*8)=tmp[kt];
    }
    __syncthreads();
    // MFMA, full K per wave: 64 MFMA, no cross-wave reduction
    f32x4 acc[2];
    acc[0]=(f32x4)(0.f); acc[1]=(f32x4)(0.f);
#pragma unroll
    for(int t=0;t<32;t++){
      int kt=t>>1, kk=t&1;
      f16x8 af0=frag_ld(As+kt*4096, mh*32,    kk*4, lane);
      f16x8 af1=frag_ld(As+kt*4096, mh*32+16, kk*4, lane);
      acc[0]=__builtin_amdgcn_mfma_f32_16x16x32_f16(af0,bw[t],acc[0],0,0,0);
      acc[1]=__builtin_amdgcn_mfma_f32_16x16x32_f16(af1,bw[t],acc[1],0,0,0);
    }
    // gates -> gs (single pass)
#pragma unroll
    for(int i=0;i<2;i++)
#pragma unroll
      for(int r=0;r<4;r++)
        gs[(mh*32+i*16+(lane>>4)*4+r)*72 + cn*16+(lane&15)]=acc[i][r];
    __syncthreads();
    // elementwise (2 cells/thread); coherent h store
    {
      float4 gv=*(const float4*)&gs[rl0*72+u0*4];
      float ii=1.f/(1.f+__expf(-(gv.x+(float)xv0[0])));
      float ff=1.f/(1.f+__expf(-(gv.y+(float)xv0[1])));
      float gg=1.f-2.f/(__expf(2.f*(gv.z+(float)xv0[2]))+1.f);
      float oo=1.f/(1.f+__expf(-(gv.w+(float)xv0[3])));
      c0=ff*c0+ii*gg;
      float th=1.f-2.f/(__expf(2.f*c0)+1.f);
      store_c2(hh + (size_t)(bm+rl0)*(CH_*H_) + dt*H_ + gu, f2h(oo*th));
    }
    {
      float4 gv=*(const float4*)&gs[rl1*72+u0*4];
      float ii=1.f/(1.f+__expf(-(gv.x+(float)xv1[0])));
      float ff=1.f/(1.f+__expf(-(gv.y+(float)xv1[1])));
      float gg=1.f-2.f/(__expf(2.f*(gv.z+(float)xv1[2]))+1.f);
      float oo=1.f/(1.f+__expf(-(gv.w+(float)xv1[3])));
      c1=ff*c1+ii*gg;
      float th=1.f-2.f/(__expf(2.f*c1)+1.f);
      store_c2(hh + (size_t)(bm+rl1)*(CH_*H_) + dt*H_ + gu, f2h(oo*th));
    }
    __syncthreads();   // gs reads done before next step overwrites
  }
  cst[(size_t)(bm+rl0)*H_+gu]=c0;
  cst[(size_t)(bm+rl1)*H_+gu]=c1;
}

// ---- fallback per-step LSTM (low-ws tier): gates = xg(fp16) + h_prev @ Whh(perm)^T.
__global__ __launch_bounds__(256,2) void lstm_step(u16* __restrict__ hh, int slotPrev, int dt,
        const void* __restrict__ Whh, const u16* __restrict__ xg,
        float* __restrict__ cst, const int* __restrict__ flag){
  int m=*flag;
  __shared__ u16 As[64*64];
  __shared__ u16 Bs[64*64];
  __shared__ float gs[64*64];
  int tid=threadIdx.x, lane=tid&63, w=tid>>6;
  int bm=blockIdx.y*64, bn=blockIdx.x*64;
  int wm=(w&1)*32, wn=(w>>1)*32;
  f32x4 acc[2][2];
#pragma unroll
  for(int i=0;i<2;i++)
#pragma unroll
    for(int j=0;j<2;j++) acc[i][j]=(f32x4)(0.f);
  for(int k0=0;k0<H_;k0+=64){
    stage<64,0>(hh + slotPrev*H_, 2, CH_*H_, k0, bm, 0, As, tid);
    stage<64,1>(Whh,              m, H_,     k0, bn, 0, Bs, tid);
    __syncthreads();
#pragma unroll
    for(int kk=0;kk<2;kk++){
      f16x8 af[2], bq[2];
#pragma unroll
      for(int i=0;i<2;i++) af[i]=frag_ld(As, wm+i*16, kk*4, lane);
#pragma unroll
      for(int j=0;j<2;j++) bq[j]=frag_ld(Bs, wn+j*16, kk*4, lane);
#pragma unroll
      for(int i=0;i<2;i++)
#pragma unroll
        for(int j=0;j<2;j++)
          acc[i][j]=__builtin_amdgcn_mfma_f32_16x16x32_f16(af[i],bq[j],acc[i][j],0,0,0);
    }
    __syncthreads();
  }
  int rl=lane>>4, cl=lane&15;
#pragma unroll
  for(int j=0;j<2;j++){
    int coll=wn+j*16+cl;
#pragma unroll
    for(int i=0;i<2;i++){
#pragma unroll
      for(int r=0;r<4;r++){
        int rowl=wm+i*16+rl*4+r;
        float xv=(float)((const _Float16*)xg)[((size_t)(bm+rowl)*CH_+dt)*G_ + bn+coll];
        gs[rowl*64+coll]=acc[i][j][r] + xv;
      }
    }
  }
  __syncthreads();
#pragma unroll
  for(int p=0;p<4;p++){
    int idx=p*256+tid;
    int rowl=idx>>4, u=idx&15;
    float4 gv = *(const float4*)&gs[rowl*64+u*4];
    float ii=1.f/(1.f+__expf(-gv.x));
    float ff=1.f/(1.f+__expf(-gv.y));
    float gg=1.f-2.f/(__expf(2.f*gv.z)+1.f);
    float oo=1.f/(1.f+__expf(-gv.w));
    int gb=bm+rowl;
    int gu=(bn>>2)+u;
    size_t ci=(size_t)gb*H_+gu;
    float cn=ff*cst[ci]+ii*gg;
    cst[ci]=cn;
    float th=1.f-2.f/(__expf(2.f*cn)+1.f);
    hh[(size_t)gb*(CH_*H_) + dt*H_ + gu]=f2h(oo*th);
  }
}

// ---- heads for one chunk: wave per row rg=b*CH_+dt; output gw=b*S+t0+dt.
__global__ __launch_bounds__(256,2) void heads_chunk(const u16* __restrict__ hh,
      const void* __restrict__ Wl, const void* __restrict__ Wv,
      const float* __restrict__ blf, const int* __restrict__ acts,
      void* __restrict__ out, const int* __restrict__ flag, int t0){
  int m=*flag;
  int rg = blockIdx.x*4 + (threadIdx.x>>6);
  int lane = threadIdx.x & 63;
  const u16* h = hh + (size_t)rg*H_;               // fp16, written via sc0sc1 -> read coherent
  u32x4 hv0=load_c16(h + lane*16);
  u32x4 hv1=load_c16(h + lane*16 + 8);
  f16x8 h0=__builtin_bit_cast(f16x8,hv0), h1=__builtin_bit_cast(f16x8,hv1);
  float hv[16];
#pragma unroll
  for(int k=0;k<8;k++){ hv[k]=(float)h0[k]; hv[8+k]=(float)h1[k]; }
  float dots[19];
#pragma unroll
  for(int j=0;j<19;j++){
    const void* wrow = (j<18) ? Wl : Wv;
    size_t roff = (j<18) ? (size_t)j*H_ : 0;
    float wv_[16];
    if(m){
      const float* f=(const float*)wrow + roff + lane*16;
      float4 a=*(const float4*)f, b=*(const float4*)(f+4), c=*(const float4*)(f+8), d=*(const float4*)(f+12);
      wv_[0]=a.x;wv_[1]=a.y;wv_[2]=a.z;wv_[3]=a.w; wv_[4]=b.x;wv_[5]=b.y;wv_[6]=b.z;wv_[7]=b.w;
      wv_[8]=c.x;wv_[9]=c.y;wv_[10]=c.z;wv_[11]=c.w; wv_[12]=d.x;wv_[13]=d.y;wv_[14]=d.z;wv_[15]=d.w;
    } else {
      const u16* ub=(const u16*)wrow + roff + lane*16;
      s16x8 w0=*(const s16x8*)ub, w1=*(const s16x8*)(ub+8);
#pragma unroll
      for(int k=0;k<8;k++){ wv_[k]=bf2f((u16)w0[k]); wv_[8+k]=bf2f((u16)w1[k]); }
    }
    float d=0.f;
#pragma unroll
    for(int k=0;k<16;k++) d += hv[k]*wv_[k];
#pragma unroll
    for(int mm=1;mm<64;mm<<=1) d += __shfl_xor(d, mm, 64);
    dots[j]=d;
  }
  float lg[18];
#pragma unroll
  for(int j=0;j<18;j++) lg[j]=dots[j]+blf[j];
  float value=dots[18]+blf[18];
  float mx=lg[0];
#pragma unroll
  for(int j=1;j<18;j++) mx=fmaxf(mx,lg[j]);
  float se=0.f, s1=0.f;
#pragma unroll
  for(int j=0;j<18;j++){ float e=__expf(lg[j]-mx); se+=e; s1+=e*(lg[j]-mx); }
  float lse=__logf(se);
  int b=rg>>4, dt=rg&(CH_-1);
  int gw = b*S_ + t0 + dt;
  int a=acts[gw];
  float la=0.f;
#pragma unroll
  for(int j=0;j<18;j++) la = (j==a) ? lg[j] : la;
  float lp=la-mx-lse;
  float ent=lse - s1/se;
  if(lane==0){
    if(m){
      ((float*)out)[gw]=lp; ((float*)out)[M_+gw]=ent; ((float*)out)[2*M_+gw]=value;
    } else {
      ((u16*)out)[gw]=f2bf(lp); ((u16*)out)[M_+gw]=f2bf(ent); ((u16*)out)[2*M_+gw]=f2bf(value);
    }
  }
}

// ---- dtype detect
__global__ void detect(const u16* __restrict__ obs_w, int* __restrict__ flag){
  __shared__ float red[256];
  float mx=0.f;
  for(int i=threadIdx.x;i<4096;i+=256) mx=fmaxf(mx,fabsf(bf2f(obs_w[i])));
  red[threadIdx.x]=mx; __syncthreads();
  for(int s=128;s>0;s>>=1){
    if(threadIdx.x<s) red[threadIdx.x]=fmaxf(red[threadIdx.x],red[threadIdx.x+s]);
    __syncthreads();
  }
  if(threadIdx.x==0) *flag=(red[0]>1e4f)?1:0;
}

// ---- prep: biases, c state, h seed (fp16, slot CH_-1), zero barrier flags.
__global__ void prep(const void* bih, const void* bhh, const void* b1, const void* bl, const void* bv,
                     const void* cx, const void* hx,
                     float* biasg, float* b1f, float* blf, float* cst, u16* hh,
                     int* cnt, const int* __restrict__ flag){
  int m=*flag;
  size_t i=(size_t)blockIdx.x*256+threadIdx.x;
  if(i<G_){ size_t rm=(i&3)*H_+(i>>2); biasg[i]=ldf(bih,rm,m)+ldf(bhh,rm,m); return; }
  i-=G_;
  if(i<H_){ b1f[i]=ldf(b1,i,m); return; }
  i-=H_;
  if(i<19){ blf[i]=(i<18)?ldf(bl,i,m):ldf(bv,0,m); return; }
  i-=19;
  if(i<512){ cnt[i]=0; return; }
  i-=512;
  if(i<(size_t)B_*H_){ cst[i]=ldf(cx,i,m); return; }
  i-=(size_t)B_*H_;
  if(i<(size_t)B_*H_){
    size_t b=i>>10, k=i&1023;
    hh[b*(CH_*H_) + (CH_-1)*H_ + k]=f2h(ldf(hx,i,m));
  }
}

// ---- weight pre-conversion to fp16 (exact from bf16), gate-permuted for Wih/Whh.
__global__ void convw(const void* W1, const void* Wih, const void* Whh,
                      u16* W1h, u16* Wihp, u16* Whhp, const int* __restrict__ flag){
  int m=*flag;
  size_t i=((size_t)blockIdx.x*256+threadIdx.x)*8;
  const size_t n1=(size_t)H_*F_, n2=(size_t)G_*H_;
  if(i<n1){ *(f16x8*)(W1h+i)=load8_h(W1,i,m); return; }
  i-=n1;
  if(i<n2){ size_t p=i>>10, c=i&1023; size_t sr=(p&3)*H_+(p>>2);
            *(f16x8*)(Wihp+i)=load8_h(Wih, sr*H_+c, m); return; }
  i-=n2;
  if(i<n2){ size_t p=i>>10, c=i&1023; size_t sr=(p&3)*H_+(p>>2);
            *(f16x8*)(Whhp+i)=load8_h(Whh, sr*H_+c, m); return; }
}
__global__ void convobs(const void* obs, u16* obsh, const int* __restrict__ flag){
  int m=*flag;
  size_t i=((size_t)blockIdx.x*256+threadIdx.x)*8;
  if(i<(size_t)M_*F_) *(f16x8*)(obsh+i)=load8_h(obs,i,m);
}

extern "C" void kernel_launch(void* const* d_in, const int* in_sizes, int n_in,
                              void* d_out, int out_size, void* d_ws, size_t ws_size,
                              hipStream_t stream){
  const void* obs=d_in[0];
  const void* hx =d_in[1];
  const void* cx =d_in[2];
  const int* acts=(const int*)d_in[3];
  const void* W1 =d_in[4];
  const void* b1 =d_in[5];
  const void* Wih=d_in[6];
  const void* bih=d_in[7];
  const void* Whh=d_in[8];
  const void* bhh=d_in[9];
  const void* Wv =d_in[10];
  const void* bv =d_in[11];
  const void* Wl =d_in[12];
  const void* bl =d_in[13];

  char* w=(char*)d_ws;
  auto alloc=[&](size_t n){ char* p=w; w+=((n+255)&~(size_t)255); return p; };
  int*   flag =(int*)alloc(4);
  int*   cnt  =(int*)alloc(512*4);                 // 4 groups x 64 flags (+spare)
  float* biasg=(float*)alloc((size_t)G_*4);
  float* b1f  =(float*)alloc((size_t)H_*4);
  float* blf  =(float*)alloc(32*4);
  float* cst  =(float*)alloc((size_t)B_*H_*4);     // 1 MB fp32 c
  u16*   hh   =(u16*)alloc((size_t)B_*CH_*H_*2);   // 8 MB fp16 h history [B][16][H]
  u16*   xc   =(u16*)alloc((size_t)CR_*H_*2);      // 8 MB fp16 x chunk
  u16*   xg   =(u16*)alloc((size_t)CR_*G_*2);      // 32 MB fp16 xg chunk
  // tiers
  size_t nW=((size_t)H_*F_ + 2*(size_t)G_*H_)*2 + 768;
  bool pathW = ((size_t)(w-(char*)d_ws) + nW) <= ws_size;
  u16 *W1h=0,*Wihp=0,*Whhp=0;
  if(pathW){ W1h=(u16*)alloc((size_t)H_*F_*2); Wihp=(u16*)alloc((size_t)G_*H_*2); Whhp=(u16*)alloc((size_t)G_*H_*2); }
  size_t nXC=(size_t)M_*H_*2 + 256;
  bool pathXC = pathW && (((size_t)(w-(char*)d_ws) + nXC) <= ws_size);
  u16* xcf=0; if(pathXC) xcf=(u16*)alloc((size_t)M_*H_*2);
  size_t nO=(size_t)M_*F_*2 + 256;
  bool pathO = pathXC && (((size_t)(w-(char*)d_ws) + nO) <= ws_size);
  u16* obsh=0; if(pathO) obsh=(u16*)alloc((size_t)M_*F_*2);

  detect<<<1,256,0,stream>>>((const u16*)obs, flag);
  {
    int total=G_+H_+19+512+B_*H_+B_*H_;
    prep<<<(total+255)/256,256,0,stream>>>(bih,bhh,b1,bl,bv,cx,hx, biasg,b1f,blf,cst,hh,cnt, flag);
  }
  if(pathW){
    size_t n=((size_t)H_*F_+2*(size_t)G_*H_)/8;
    convw<<<(int)((n+255)/256),256,0,stream>>>(W1,Wih,Whh, W1h,Wihp,Whhp, flag);
  }
  if(pathO){
    size_t n=(size_t)M_*F_/8;
    convobs<<<(int)((n+255)/256),256,0,stream>>>(obs, obsh, flag);
  }
  if(pathXC){
    gemm128<0,0,0><<<dim3(H_/128, M_/128),256,0,stream>>>(
        pathO?(const void*)obsh:obs, pathW?(const void*)W1h:W1, xcf, b1f, flag,
        F_, F_, F_, H_, 0, pathO?2:-1, pathW?2:-1);
  }

  for(int c=0;c<S_/CH_;c++){
    int t0=c*CH_;
    if(!pathXC){
      gemm128<2,0,0><<<dim3(H_/128, CR_/128),256,0,stream>>>(
          obs, pathW?(const void*)W1h:W1, xc, b1f, flag, F_, F_, F_, H_, t0, -1, pathW?2:-1);
    }
    if(pathXC)
      gemm128<2,0,2><<<dim3(G_/128, CR_/128),256,0,stream>>>(
          xcf, Wihp, xg, biasg, flag, H_, H_, H_, G_, t0, 2, 2);
    else if(pathW)
      gemm128<0,0,2><<<dim3(G_/128, CR_/128),256,0,stream>>>(
          xc, Wihp, xg, biasg, flag, H_, H_, H_, G_, 0, 2, 2);
    else
      gemm128<0,1,2><<<dim3(G_/128, CR_/128),256,0,stream>>>(
          xc, Wih, xg, biasg, flag, H_, H_, H_, G_, 0, 2, -1);

    if(pathW)
      lstm_persist<<<256,512,0,stream>>>(hh, Whhp, xg, cst, cnt, t0);
    else
      for(int dt=0;dt<CH_;dt++)
        lstm_step<<<dim3(G_/64, B_/64),256,0,stream>>>(hh, (dt+CH_-1)&(CH_-1), dt, Whh, xg, cst, flag);

    heads_chunk<<<dim3(CR_/4),256,0,stream>>>(hh, Wl, Wv, blf, acts, d_out, flag, t0);
  }
}

// Round 10
// 1219.565 us; speedup vs baseline: 5.6550x; 1.1196x over previous
//
#include <hip/hip_runtime.h>

#define B_ 256
#define S_ 128
#define F_ 512
#define H_ 1024
#define A_ 18
#define M_ (B_*S_)      // 32768 output rows (b*S+s)
#define G_ (4*H_)       // 4096 gate cols, permuted unit-major: p = unit*4 + {i,f,g,o}
#define CH_ 16          // timesteps per chunk
#define CR_ (B_*CH_)    // 4096 rows per chunk, row rg = b*CH_ + dt

typedef unsigned short u16;
typedef __attribute__((ext_vector_type(8))) _Float16 f16x8;  // 8 fp16 = 4 VGPR
typedef __attribute__((ext_vector_type(4))) _Float16 f16x4;
typedef __attribute__((ext_vector_type(8))) short   s16x8;
typedef __attribute__((ext_vector_type(4))) float f32x4;
typedef __attribute__((ext_vector_type(4))) unsigned int u32x4;

__device__ __forceinline__ float bf2f(u16 u){
  union{unsigned int i; float f;} v; v.i=((unsigned int)u)<<16; return v.f;
}
__device__ __forceinline__ u16 f2bf(float f){
  unsigned int i=__float_as_uint(f);
  unsigned int r=(i+0x7fffu+((i>>16)&1u))>>16;   // RNE
  return (u16)r;
}
__device__ __forceinline__ u16 f2h(float f){
  _Float16 h=(_Float16)f;
  union{_Float16 h; u16 u;} v; v.h=h; return v.u;
}
// mode-aware scalar load of logical float element i (1: fp32, 0: bf16)
__device__ __forceinline__ float ldf(const void* p, size_t i, int m){
  return m ? ((const float*)p)[i] : bf2f(((const u16*)p)[i]);
}
// load 8 logical floats -> fp16x8. mode 0: bf16 src, 1: fp32 src, 2: raw fp16 src.
__device__ __forceinline__ f16x8 load8_h(const void* base, size_t off, int m){
  f16x8 v;
  if(m==2) return *(const f16x8*)((const u16*)base + off);
  if(m==1){
    const float* f=(const float*)base + off;
    float4 a=*(const float4*)f; float4 b=*(const float4*)(f+4);
    v[0]=(_Float16)a.x; v[1]=(_Float16)a.y; v[2]=(_Float16)a.z; v[3]=(_Float16)a.w;
    v[4]=(_Float16)b.x; v[5]=(_Float16)b.y; v[6]=(_Float16)b.z; v[7]=(_Float16)b.w;
    return v;
  }
  s16x8 w=*(const s16x8*)((const u16*)base + off);
#pragma unroll
  for(int k=0;k<8;k++) v[k]=(_Float16)bf2f((u16)w[k]);
  return v;
}

// ---- coherent (cross-XCD, LLC-routed) accesses: bypass L1+L2 via sc0 sc1.
__device__ __forceinline__ u32x4 load_c16(const void* p){
  u32x4 r;
  asm volatile("global_load_dwordx4 %0, %1, off sc0 sc1" : "=v"(r) : "v"(p));
  return r;
}
__device__ __forceinline__ void store_c2(u16* p, u16 v){
  unsigned int vv=v;
  asm volatile("global_store_short %0, %1, off sc0 sc1" :: "v"(p), "v"(vv) : "memory");
}
__device__ __forceinline__ int load_c4(const int* p){
  int r;
  asm volatile("global_load_dword %0, %1, off sc0 sc1" : "=v"(r) : "v"(p));
  return r;
}
__device__ __forceinline__ void store_c4(int* p, int v){
  asm volatile("global_store_dword %0, %1, off sc0 sc1" :: "v"(p), "v"(v) : "memory");
}

// ---- store-flag group barrier (32 blocks): arrival = own-flag store (monotonic target),
// departure = wave-0 parallel poll of 32 flags (lanes 32-63 duplicate lanes 0-31).
__device__ __forceinline__ void bar_flags32(int* flags, int target, int gi, int lane, int w){
  asm volatile("s_waitcnt vmcnt(0)" ::: "memory");   // own h stores at LLC
  __syncthreads();
  if(w==0){
    if(lane==0) store_c4(flags+gi, target);
    while(true){
      int v=load_c4(flags+(lane&31));
      asm volatile("s_waitcnt vmcnt(0)" ::: "memory");
      if(__all(v>=target)) break;
      __builtin_amdgcn_s_sleep(1);
    }
  }
  __syncthreads();
}

// ---- Stage ROWS x 64 fp16 tile into LDS [ROWS][64], XOR-swizzled 16B chunks (256-thr blocks).
// mode 2: global_load_lds direct (linear dest, inverse-swizzled per-lane src).
// MAP 0: src row = rowoff+r. MAP 1: p=rowoff+r -> (p&3)*H_+(p>>2). MAP 2: p -> (p>>4)*S_+t0+(p&15).
template<int ROWS, int MAP>
__device__ __forceinline__ void stage(const void* base, int mode, int lda, int k0,
                                      int rowoff, int t0, u16* lds, int tid){
  if(mode==2){
    constexpr int NI=(ROWS*8)/256;
    int wv=tid>>6, l=tid&63;
#pragma unroll
    for(int i=0;i<NI;i++){
      int s0=i*256+(wv<<6), s=s0+l;
      int r=s>>3, gc=(s&7)^(r&7);
      int p=rowoff+r, sr;
      if(MAP==0)      sr=p;
      else if(MAP==1) sr=(p&3)*H_+(p>>2);
      else            sr=(p>>4)*S_+t0+(p&15);
      const u16* src=(const u16*)base + (size_t)sr*lda + k0 + gc*8;
      u16* dst=lds + s0*8;             // wave-uniform; HW adds lane*16B
      __builtin_amdgcn_global_load_lds((const __attribute__((address_space(1))) unsigned int*)src,
                                       (__attribute__((address_space(3))) unsigned int*)dst,
                                       16, 0, 0);
    }
  } else {
#pragma unroll
    for(int s0=tid; s0<ROWS*8; s0+=256){
      int r=s0>>3, gc=s0&7, lc=gc^(r&7);
      int p=rowoff+r, sr;
      if(MAP==0)      sr=p;
      else if(MAP==1) sr=(p&3)*H_+(p>>2);
      else            sr=(p>>4)*S_+t0+(p&15);
      f16x8 v=load8_h(base, (size_t)sr*lda + k0 + gc*8, mode);
      *(f16x8*)(lds + r*64 + lc*8)=v;
    }
  }
}

// MFMA 16x16x32 fragment from swizzled LDS tile: lane -> row r0+(l&15), chunk kc+(l>>4), un-XOR.
__device__ __forceinline__ f16x8 frag_ld(const u16* lds, int r0, int kc, int lane){
  int r = r0 + (lane&15);
  int c = (kc + (lane>>4)) ^ (r&7);
  return *(const f16x8*)(lds + r*64 + c*8);
}

// ---- 128x128-tile GEMM: C = A * B^T + biasf. amode/bmode: <0 -> *flag, else literal.
// OUTMODE 0: relu+fp16. 1: fp32. 2: fp16 (no relu).
template<int AMAP, int BMAP, int OUTMODE>
__global__ __launch_bounds__(256,3) void gemm128(const void* A, const void* Bt, void* C,
    const float* __restrict__ biasf, const int* __restrict__ flag,
    int K, int lda, int ldb, int ldc, int t0, int amode, int bmode){
  int m=*flag;
  int am = amode<0 ? m : amode;
  int bm_ = bmode<0 ? m : bmode;
  __shared__ u16 As[128*64];
  __shared__ u16 Bs[128*64];
  int tid=threadIdx.x, lane=tid&63, w=tid>>6;
  int bm=blockIdx.y*128, bn=blockIdx.x*128;
  int wm=(w&1)*64, wn=(w>>1)*64;
  f32x4 acc[4][4];
#pragma unroll
  for(int i=0;i<4;i++)
#pragma unroll
    for(int j=0;j<4;j++) acc[i][j]=(f32x4)(0.f);
  for(int k0=0;k0<K;k0+=64){
    stage<128,AMAP>(A , am,  lda, k0, bm, t0, As, tid);
    stage<128,BMAP>(Bt, bm_, ldb, k0, bn, t0, Bs, tid);
    __syncthreads();
#pragma unroll
    for(int kk=0;kk<2;kk++){
      f16x8 af[4], bq[4];
#pragma unroll
      for(int i=0;i<4;i++) af[i]=frag_ld(As, wm+i*16, kk*4, lane);
#pragma unroll
      for(int j=0;j<4;j++) bq[j]=frag_ld(Bs, wn+j*16, kk*4, lane);
#pragma unroll
      for(int i=0;i<4;i++)
#pragma unroll
        for(int j=0;j<4;j++)
          acc[i][j]=__builtin_amdgcn_mfma_f32_16x16x32_f16(af[i],bq[j],acc[i][j],0,0,0);
    }
    __syncthreads();
  }
  int rl=lane>>4, cl=lane&15;
#pragma unroll
  for(int j=0;j<4;j++){
    int col=bn+wn+j*16+cl;
    float bb=biasf[col];
#pragma unroll
    for(int i=0;i<4;i++){
#pragma unroll
      for(int r=0;r<4;r++){
        int row=bm+wm+i*16+rl*4+r;
        float v=acc[i][j][r]+bb;
        if(OUTMODE==0){ v=fmaxf(v,0.f); ((u16*)C)[(size_t)row*ldc+col]=f2h(v); }
        else if(OUTMODE==2){ ((u16*)C)[(size_t)row*ldc+col]=f2h(v); }
        else { ((float*)C)[(size_t)row*ldc+col]=v; }
      }
    }
  }
}

// ---- persistent chunk-LSTM v6: 8 groups x 32 batches, block = 32 batches x 128 cols.
// Grid 256 (1/CU), 512 threads. grp=blockIdx&7 (bm=grp*32), ci=blockIdx>>3 (bn=ci*128).
// Wave w (0..7): cols bn+w*16..+15, all 32 rows, full K=1024. Whh pinned in AGPRs.
// Halves LLC stage traffic (64KB/block/step) and barrier size (32) vs v5.
__global__ __launch_bounds__(512,2) void lstm_persist(u16* __restrict__ hh,
        const u16* __restrict__ Whhp, const u16* __restrict__ xgp,
        float* __restrict__ cst, int* __restrict__ cntc, int tbase){
  __shared__ u16 As[16*2048];     // 64 KB: 16 k-tiles [32][64], XOR-swizzled
  __shared__ float gs[32*132];    // 16.9 KB, stride 132
  int tid=threadIdx.x, lane=tid&63, w=tid>>6;
  int grp=blockIdx.x&7, ci=blockIdx.x>>3;
  int bm=grp*32, bn=ci*128;
  int* flags = cntc + grp*64;

  // Whh slice -> 32 f16x8 (wave's 16 cols x K=1024), pinned in AGPRs.
  f16x8 bw[32];
#pragma unroll
  for(int t=0;t<32;t++){
    int p = bn + w*16 + (lane&15);
    int k = t*32 + (lane>>4)*8;
    bw[t]=*(const f16x8*)(Whhp + (size_t)p*H_ + k);
  }
#pragma unroll
  for(int t=0;t<32;t++) asm volatile("" : "+a"(bw[t]));

  // cells: 32 rows x 32 units = 1024; thread owns (rl0,u0) and (rl1,u0).
  int rl0=tid>>5, rl1=(tid+512)>>5, u0=tid&31;
  int gu=(bn>>2)+u0;
  float c0=cst[(size_t)(bm+rl0)*H_+gu];
  float c1=cst[(size_t)(bm+rl1)*H_+gu];

  for(int dt=0;dt<CH_;dt++){
    // xg prefetch (fp16, cached) — independent of h, issued BEFORE the barrier
    f16x4 xv0=*(const f16x4*)(xgp + ((size_t)(bm+rl0)*CH_+dt)*G_ + bn + u0*4);
    f16x4 xv1=*(const f16x4*)(xgp + ((size_t)(bm+rl1)*CH_+dt)*G_ + bn + u0*4);
    if(dt) bar_flags32(flags, tbase+dt, ci, lane, w);
    // stage h_prev[32][1024]: 8 coherent 16B loads/thread -> regs -> LDS (swizzled)
    {
      int slotPrev=(dt+CH_-1)&(CH_-1);
      u32x4 tmp[8];
#pragma unroll
      for(int i=0;i<8;i++){
        int s=tid+i*512, kt=s>>8, r=(s>>3)&31, gc=s&7;
        tmp[i]=load_c16(hh + ((size_t)(bm+r)*CH_+slotPrev)*H_ + kt*64 + gc*8);
      }
      asm volatile("s_waitcnt vmcnt(0)" ::: "memory");
#pragma unroll
      for(int i=0;i<8;i++){
        int s=tid+i*512, kt=s>>8, r=(s>>3)&31, gc=s&7, lc=gc^(r&7);
        *(u32x4*)(As + kt*2048 + r*64 + lc*8)=tmp[i];
      }
    }
    __syncthreads();
    // MFMA, full K per wave: 64 MFMA, no cross-wave reduction
    f32x4 acc0=(f32x4)(0.f), acc1=(f32x4)(0.f);
#pragma unroll
    for(int t=0;t<32;t++){
      int kt=t>>1, kk=t&1;
      f16x8 af0=frag_ld(As+kt*2048, 0,  kk*4, lane);
      f16x8 af1=frag_ld(As+kt*2048, 16, kk*4, lane);
      acc0=__builtin_amdgcn_mfma_f32_16x16x32_f16(af0,bw[t],acc0,0,0,0);
      acc1=__builtin_amdgcn_mfma_f32_16x16x32_f16(af1,bw[t],acc1,0,0,0);
    }
    // gates -> gs (single pass); C/D: col=lane&15, row=(lane>>4)*4+r
#pragma unroll
    for(int r=0;r<4;r++){
      gs[(   (lane>>4)*4+r)*132 + w*16+(lane&15)]=acc0[r];
      gs[(16+(lane>>4)*4+r)*132 + w*16+(lane&15)]=acc1[r];
    }
    __syncthreads();
    // elementwise (2 cells/thread); coherent h store
    {
      float4 gv=*(const float4*)&gs[rl0*132+u0*4];
      float ii=1.f/(1.f+__expf(-(gv.x+(float)xv0[0])));
      float ff=1.f/(1.f+__expf(-(gv.y+(float)xv0[1])));
      float gg=1.f-2.f/(__expf(2.f*(gv.z+(float)xv0[2]))+1.f);
      float oo=1.f/(1.f+__expf(-(gv.w+(float)xv0[3])));
      c0=ff*c0+ii*gg;
      float th=1.f-2.f/(__expf(2.f*c0)+1.f);
      store_c2(hh + ((size_t)(bm+rl0)*CH_+dt)*H_ + gu, f2h(oo*th));
    }
    {
      float4 gv=*(const float4*)&gs[rl1*132+u0*4];
      float ii=1.f/(1.f+__expf(-(gv.x+(float)xv1[0])));
      float ff=1.f/(1.f+__expf(-(gv.y+(float)xv1[1])));
      float gg=1.f-2.f/(__expf(2.f*(gv.z+(float)xv1[2]))+1.f);
      float oo=1.f/(1.f+__expf(-(gv.w+(float)xv1[3])));
      c1=ff*c1+ii*gg;
      float th=1.f-2.f/(__expf(2.f*c1)+1.f);
      store_c2(hh + ((size_t)(bm+rl1)*CH_+dt)*H_ + gu, f2h(oo*th));
    }
    // next bar_flags32's __syncthreads orders gs reads vs next step's writes
  }
  cst[(size_t)(bm+rl0)*H_+gu]=c0;
  cst[(size_t)(bm+rl1)*H_+gu]=c1;
}

// ---- fallback per-step LSTM (low-ws tier): gates = xg(fp16) + h_prev @ Whh(perm)^T.
__global__ __launch_bounds__(256,2) void lstm_step(u16* __restrict__ hh, int slotPrev, int dt,
        const void* __restrict__ Whh, const u16* __restrict__ xg,
        float* __restrict__ cst, const int* __restrict__ flag){
  int m=*flag;
  __shared__ u16 As[64*64];
  __shared__ u16 Bs[64*64];
  __shared__ float gs[64*64];
  int tid=threadIdx.x, lane=tid&63, w=tid>>6;
  int bm=blockIdx.y*64, bn=blockIdx.x*64;
  int wm=(w&1)*32, wn=(w>>1)*32;
  f32x4 acc[2][2];
#pragma unroll
  for(int i=0;i<2;i++)
#pragma unroll
    for(int j=0;j<2;j++) acc[i][j]=(f32x4)(0.f);
  for(int k0=0;k0<H_;k0+=64){
    stage<64,0>(hh + slotPrev*H_, 2, CH_*H_, k0, bm, 0, As, tid);
    stage<64,1>(Whh,              m, H_,     k0, bn, 0, Bs, tid);
    __syncthreads();
#pragma unroll
    for(int kk=0;kk<2;kk++){
      f16x8 af[2], bq[2];
#pragma unroll
      for(int i=0;i<2;i++) af[i]=frag_ld(As, wm+i*16, kk*4, lane);
#pragma unroll
      for(int j=0;j<2;j++) bq[j]=frag_ld(Bs, wn+j*16, kk*4, lane);
#pragma unroll
      for(int i=0;i<2;i++)
#pragma unroll
        for(int j=0;j<2;j++)
          acc[i][j]=__builtin_amdgcn_mfma_f32_16x16x32_f16(af[i],bq[j],acc[i][j],0,0,0);
    }
    __syncthreads();
  }
  int rl=lane>>4, cl=lane&15;
#pragma unroll
  for(int j=0;j<2;j++){
    int coll=wn+j*16+cl;
#pragma unroll
    for(int i=0;i<2;i++){
#pragma unroll
      for(int r=0;r<4;r++){
        int rowl=wm+i*16+rl*4+r;
        float xv=(float)((const _Float16*)xg)[((size_t)(bm+rowl)*CH_+dt)*G_ + bn+coll];
        gs[rowl*64+coll]=acc[i][j][r] + xv;
      }
    }
  }
  __syncthreads();
#pragma unroll
  for(int p=0;p<4;p++){
    int idx=p*256+tid;
    int rowl=idx>>4, u=idx&15;
    float4 gv = *(const float4*)&gs[rowl*64+u*4];
    float ii=1.f/(1.f+__expf(-gv.x));
    float ff=1.f/(1.f+__expf(-gv.y));
    float gg=1.f-2.f/(__expf(2.f*gv.z)+1.f);
    float oo=1.f/(1.f+__expf(-gv.w));
    int gb=bm+rowl;
    int gu=(bn>>2)+u;
    size_t ci=(size_t)gb*H_+gu;
    float cn=ff*cst[ci]+ii*gg;
    cst[ci]=cn;
    float th=1.f-2.f/(__expf(2.f*cn)+1.f);
    hh[(size_t)gb*(CH_*H_) + dt*H_ + gu]=f2h(oo*th);
  }
}

// ---- heads for one chunk: wave per row rg=b*CH_+dt; output gw=b*S+t0+dt.
__global__ __launch_bounds__(256,2) void heads_chunk(const u16* __restrict__ hh,
      const void* __restrict__ Wl, const void* __restrict__ Wv,
      const float* __restrict__ blf, const int* __restrict__ acts,
      void* __restrict__ out, const int* __restrict__ flag, int t0){
  int m=*flag;
  int rg = blockIdx.x*4 + (threadIdx.x>>6);
  int lane = threadIdx.x & 63;
  const u16* h = hh + (size_t)rg*H_;               // fp16, written via sc0sc1 -> read coherent
  u32x4 hv0=load_c16(h + lane*16);
  u32x4 hv1=load_c16(h + lane*16 + 8);
  f16x8 h0=__builtin_bit_cast(f16x8,hv0), h1=__builtin_bit_cast(f16x8,hv1);
  float hv[16];
#pragma unroll
  for(int k=0;k<8;k++){ hv[k]=(float)h0[k]; hv[8+k]=(float)h1[k]; }
  float dots[19];
#pragma unroll
  for(int j=0;j<19;j++){
    const void* wrow = (j<18) ? Wl : Wv;
    size_t roff = (j<18) ? (size_t)j*H_ : 0;
    float wv_[16];
    if(m){
      const float* f=(const float*)wrow + roff + lane*16;
      float4 a=*(const float4*)f, b=*(const float4*)(f+4), c=*(const float4*)(f+8), d=*(const float4*)(f+12);
      wv_[0]=a.x;wv_[1]=a.y;wv_[2]=a.z;wv_[3]=a.w; wv_[4]=b.x;wv_[5]=b.y;wv_[6]=b.z;wv_[7]=b.w;
      wv_[8]=c.x;wv_[9]=c.y;wv_[10]=c.z;wv_[11]=c.w; wv_[12]=d.x;wv_[13]=d.y;wv_[14]=d.z;wv_[15]=d.w;
    } else {
      const u16* ub=(const u16*)wrow + roff + lane*16;
      s16x8 w0=*(const s16x8*)ub, w1=*(const s16x8*)(ub+8);
#pragma unroll
      for(int k=0;k<8;k++){ wv_[k]=bf2f((u16)w0[k]); wv_[8+k]=bf2f((u16)w1[k]); }
    }
    float d=0.f;
#pragma unroll
    for(int k=0;k<16;k++) d += hv[k]*wv_[k];
#pragma unroll
    for(int mm=1;mm<64;mm<<=1) d += __shfl_xor(d, mm, 64);
    dots[j]=d;
  }
  float lg[18];
#pragma unroll
  for(int j=0;j<18;j++) lg[j]=dots[j]+blf[j];
  float value=dots[18]+blf[18];
  float mx=lg[0];
#pragma unroll
  for(int j=1;j<18;j++) mx=fmaxf(mx,lg[j]);
  float se=0.f, s1=0.f;
#pragma unroll
  for(int j=0;j<18;j++){ float e=__expf(lg[j]-mx); se+=e; s1+=e*(lg[j]-mx); }
  float lse=__logf(se);
  int b=rg>>4, dt=rg&(CH_-1);
  int gw = b*S_ + t0 + dt;
  int a=acts[gw];
  float la=0.f;
#pragma unroll
  for(int j=0;j<18;j++) la = (j==a) ? lg[j] : la;
  float lp=la-mx-lse;
  float ent=lse - s1/se;
  if(lane==0){
    if(m){
      ((float*)out)[gw]=lp; ((float*)out)[M_+gw]=ent; ((float*)out)[2*M_+gw]=value;
    } else {
      ((u16*)out)[gw]=f2bf(lp); ((u16*)out)[M_+gw]=f2bf(ent); ((u16*)out)[2*M_+gw]=f2bf(value);
    }
  }
}

// ---- dtype detect
__global__ void detect(const u16* __restrict__ obs_w, int* __restrict__ flag){
  __shared__ float red[256];
  float mx=0.f;
  for(int i=threadIdx.x;i<4096;i+=256) mx=fmaxf(mx,fabsf(bf2f(obs_w[i])));
  red[threadIdx.x]=mx; __syncthreads();
  for(int s=128;s>0;s>>=1){
    if(threadIdx.x<s) red[threadIdx.x]=fmaxf(red[threadIdx.x],red[threadIdx.x+s]);
    __syncthreads();
  }
  if(threadIdx.x==0) *flag=(red[0]>1e4f)?1:0;
}

// ---- prep: biases, c state, h seed (fp16, slot CH_-1), zero barrier flags.
__global__ void prep(const void* bih, const void* bhh, const void* b1, const void* bl, const void* bv,
                     const void* cx, const void* hx,
                     float* biasg, float* b1f, float* blf, float* cst, u16* hh,
                     int* cnt, const int* __restrict__ flag){
  int m=*flag;
  size_t i=(size_t)blockIdx.x*256+threadIdx.x;
  if(i<G_){ size_t rm=(i&3)*H_+(i>>2); biasg[i]=ldf(bih,rm,m)+ldf(bhh,rm,m); return; }
  i-=G_;
  if(i<H_){ b1f[i]=ldf(b1,i,m); return; }
  i-=H_;
  if(i<19){ blf[i]=(i<18)?ldf(bl,i,m):ldf(bv,0,m); return; }
  i-=19;
  if(i<512){ cnt[i]=0; return; }
  i-=512;
  if(i<(size_t)B_*H_){ cst[i]=ldf(cx,i,m); return; }
  i-=(size_t)B_*H_;
  if(i<(size_t)B_*H_){
    size_t b=i>>10, k=i&1023;
    hh[b*(CH_*H_) + (CH_-1)*H_ + k]=f2h(ldf(hx,i,m));
  }
}

// ---- weight pre-conversion to fp16 (exact from bf16), gate-permuted for Wih/Whh.
__global__ void convw(const void* W1, const void* Wih, const void* Whh,
                      u16* W1h, u16* Wihp, u16* Whhp, const int* __restrict__ flag){
  int m=*flag;
  size_t i=((size_t)blockIdx.x*256+threadIdx.x)*8;
  const size_t n1=(size_t)H_*F_, n2=(size_t)G_*H_;
  if(i<n1){ *(f16x8*)(W1h+i)=load8_h(W1,i,m); return; }
  i-=n1;
  if(i<n2){ size_t p=i>>10, c=i&1023; size_t sr=(p&3)*H_+(p>>2);
            *(f16x8*)(Wihp+i)=load8_h(Wih, sr*H_+c, m); return; }
  i-=n2;
  if(i<n2){ size_t p=i>>10, c=i&1023; size_t sr=(p&3)*H_+(p>>2);
            *(f16x8*)(Whhp+i)=load8_h(Whh, sr*H_+c, m); return; }
}
__global__ void convobs(const void* obs, u16* obsh, const int* __restrict__ flag){
  int m=*flag;
  size_t i=((size_t)blockIdx.x*256+threadIdx.x)*8;
  if(i<(size_t)M_*F_) *(f16x8*)(obsh+i)=load8_h(obs,i,m);
}

extern "C" void kernel_launch(void* const* d_in, const int* in_sizes, int n_in,
                              void* d_out, int out_size, void* d_ws, size_t ws_size,
                              hipStream_t stream){
  const void* obs=d_in[0];
  const void* hx =d_in[1];
  const void* cx =d_in[2];
  const int* acts=(const int*)d_in[3];
  const void* W1 =d_in[4];
  const void* b1 =d_in[5];
  const void* Wih=d_in[6];
  const void* bih=d_in[7];
  const void* Whh=d_in[8];
  const void* bhh=d_in[9];
  const void* Wv =d_in[10];
  const void* bv =d_in[11];
  const void* Wl =d_in[12];
  const void* bl =d_in[13];

  char* w=(char*)d_ws;
  auto alloc=[&](size_t n){ char* p=w; w+=((n+255)&~(size_t)255); return p; };
  int*   flag =(int*)alloc(4);
  int*   cnt  =(int*)alloc(512*4);                 // 8 groups x 64 flag slots (32 used)
  float* biasg=(float*)alloc((size_t)G_*4);
  float* b1f  =(float*)alloc((size_t)H_*4);
  float* blf  =(float*)alloc(32*4);
  float* cst  =(float*)alloc((size_t)B_*H_*4);     // 1 MB fp32 c
  u16*   hh   =(u16*)alloc((size_t)B_*CH_*H_*2);   // 8 MB fp16 h history [B][16][H]
  u16*   xc   =(u16*)alloc((size_t)CR_*H_*2);      // 8 MB fp16 x chunk
  u16*   xg   =(u16*)alloc((size_t)CR_*G_*2);      // 32 MB fp16 xg chunk
  // tiers
  size_t nW=((size_t)H_*F_ + 2*(size_t)G_*H_)*2 + 768;
  bool pathW = ((size_t)(w-(char*)d_ws) + nW) <= ws_size;
  u16 *W1h=0,*Wihp=0,*Whhp=0;
  if(pathW){ W1h=(u16*)alloc((size_t)H_*F_*2); Wihp=(u16*)alloc((size_t)G_*H_*2); Whhp=(u16*)alloc((size_t)G_*H_*2); }
  size_t nXC=(size_t)M_*H_*2 + 256;
  bool pathXC = pathW && (((size_t)(w-(char*)d_ws) + nXC) <= ws_size);
  u16* xcf=0; if(pathXC) xcf=(u16*)alloc((size_t)M_*H_*2);
  size_t nO=(size_t)M_*F_*2 + 256;
  bool pathO = pathXC && (((size_t)(w-(char*)d_ws) + nO) <= ws_size);
  u16* obsh=0; if(pathO) obsh=(u16*)alloc((size_t)M_*F_*2);

  detect<<<1,256,0,stream>>>((const u16*)obs, flag);
  {
    int total=G_+H_+19+512+B_*H_+B_*H_;
    prep<<<(total+255)/256,256,0,stream>>>(bih,bhh,b1,bl,bv,cx,hx, biasg,b1f,blf,cst,hh,cnt, flag);
  }
  if(pathW){
    size_t n=((size_t)H_*F_+2*(size_t)G_*H_)/8;
    convw<<<(int)((n+255)/256),256,0,stream>>>(W1,Wih,Whh, W1h,Wihp,Whhp, flag);
  }
  if(pathO){
    size_t n=(size_t)M_*F_/8;
    convobs<<<(int)((n+255)/256),256,0,stream>>>(obs, obsh, flag);
  }
  if(pathXC){
    gemm128<0,0,0><<<dim3(H_/128, M_/128),256,0,stream>>>(
        pathO?(const void*)obsh:obs, pathW?(const void*)W1h:W1, xcf, b1f, flag,
        F_, F_, F_, H_, 0, pathO?2:-1, pathW?2:-1);
  }

  for(int c=0;c<S_/CH_;c++){
    int t0=c*CH_;
    if(!pathXC){
      gemm128<2,0,0><<<dim3(H_/128, CR_/128),256,0,stream>>>(
          obs, pathW?(const void*)W1h:W1, xc, b1f, flag, F_, F_, F_, H_, t0, -1, pathW?2:-1);
    }
    if(pathXC)
      gemm128<2,0,2><<<dim3(G_/128, CR_/128),256,0,stream>>>(
          xcf, Wihp, xg, biasg, flag, H_, H_, H_, G_, t0, 2, 2);
    else if(pathW)
      gemm128<0,0,2><<<dim3(G_/128, CR_/128),256,0,stream>>>(
          xc, Wihp, xg, biasg, flag, H_, H_, H_, G_, 0, 2, 2);
    else
      gemm128<0,1,2><<<dim3(G_/128, CR_/128),256,0,stream>>>(
          xc, Wih, xg, biasg, flag, H_, H_, H_, G_, 0, 2, -1);

    if(pathW)
      lstm_persist<<<256,512,0,stream>>>(hh, Whhp, xg, cst, cnt, t0);
    else
      for(int dt=0;dt<CH_;dt++)
        lstm_step<<<dim3(G_/64, B_/64),256,0,stream>>>(hh, (dt+CH_-1)&(CH_-1), dt, Whh, xg, cst, flag);

    heads_chunk<<<dim3(CR_/4),256,0,stream>>>(hh, Wl, Wv, blf, acts, d_out, flag, t0);
  }
}

// Round 11
// 1205.313 us; speedup vs baseline: 5.7219x; 1.0118x over previous
//
#include <hip/hip_runtime.h>

#define B_ 256
#define S_ 128
#define F_ 512
#define H_ 1024
#define A_ 18
#define M_ (B_*S_)      // 32768 output rows (b*S+s)
#define G_ (4*H_)       // 4096 gate cols, permuted unit-major: p = unit*4 + {i,f,g,o}
#define CH_ 16          // timesteps per chunk
#define CR_ (B_*CH_)    // 4096 rows per chunk, row rg = b*CH_ + dt

typedef unsigned short u16;
typedef __attribute__((ext_vector_type(8))) _Float16 f16x8;  // 8 fp16 = 4 VGPR
typedef __attribute__((ext_vector_type(4))) _Float16 f16x4;
typedef __attribute__((ext_vector_type(8))) short   s16x8;
typedef __attribute__((ext_vector_type(4))) float f32x4;
typedef __attribute__((ext_vector_type(4))) unsigned int u32x4;

__device__ __forceinline__ float bf2f(u16 u){
  union{unsigned int i; float f;} v; v.i=((unsigned int)u)<<16; return v.f;
}
__device__ __forceinline__ u16 f2bf(float f){
  unsigned int i=__float_as_uint(f);
  unsigned int r=(i+0x7fffu+((i>>16)&1u))>>16;   // RNE
  return (u16)r;
}
__device__ __forceinline__ u16 f2h(float f){
  _Float16 h=(_Float16)f;
  union{_Float16 h; u16 u;} v; v.h=h; return v.u;
}
// mode-aware scalar load of logical float element i (1: fp32, 0: bf16)
__device__ __forceinline__ float ldf(const void* p, size_t i, int m){
  return m ? ((const float*)p)[i] : bf2f(((const u16*)p)[i]);
}
// load 8 logical floats -> fp16x8. mode 0: bf16 src, 1: fp32 src, 2: raw fp16 src.
__device__ __forceinline__ f16x8 load8_h(const void* base, size_t off, int m){
  f16x8 v;
  if(m==2) return *(const f16x8*)((const u16*)base + off);
  if(m==1){
    const float* f=(const float*)base + off;
    float4 a=*(const float4*)f; float4 b=*(const float4*)(f+4);
    v[0]=(_Float16)a.x; v[1]=(_Float16)a.y; v[2]=(_Float16)a.z; v[3]=(_Float16)a.w;
    v[4]=(_Float16)b.x; v[5]=(_Float16)b.y; v[6]=(_Float16)b.z; v[7]=(_Float16)b.w;
    return v;
  }
  s16x8 w=*(const s16x8*)((const u16*)base + off);
#pragma unroll
  for(int k=0;k<8;k++) v[k]=(_Float16)bf2f((u16)w[k]);
  return v;
}

// ---- coherent (cross-XCD, LLC-routed) accesses: bypass L1+L2 via sc0 sc1.
__device__ __forceinline__ u32x4 load_c16(const void* p){
  u32x4 r;
  asm volatile("global_load_dwordx4 %0, %1, off sc0 sc1" : "=v"(r) : "v"(p));
  return r;
}
__device__ __forceinline__ void store_c2(u16* p, u16 v){
  unsigned int vv=v;
  asm volatile("global_store_short %0, %1, off sc0 sc1" :: "v"(p), "v"(vv) : "memory");
}
__device__ __forceinline__ int load_c4(const int* p){
  int r;
  asm volatile("global_load_dword %0, %1, off sc0 sc1" : "=v"(r) : "v"(p));
  return r;
}
__device__ __forceinline__ void store_c4(int* p, int v){
  asm volatile("global_store_dword %0, %1, off sc0 sc1" :: "v"(p), "v"(v) : "memory");
}

// ---- store-flag group barrier (32 blocks): arrival = own-flag store (monotonic target),
// departure = wave-0 parallel poll of 32 flags (lanes 32-63 duplicate lanes 0-31).
__device__ __forceinline__ void bar_flags32(int* flags, int target, int gi, int lane, int w){
  asm volatile("s_waitcnt vmcnt(0)" ::: "memory");   // own h stores at LLC
  __syncthreads();
  if(w==0){
    if(lane==0) store_c4(flags+gi, target);
    while(true){
      int v=load_c4(flags+(lane&31));
      asm volatile("s_waitcnt vmcnt(0)" ::: "memory");
      if(__all(v>=target)) break;
      __builtin_amdgcn_s_sleep(1);
    }
  }
  __syncthreads();
}

// ---- Stage ROWS x 64 fp16 tile into LDS [ROWS][64], XOR-swizzled 16B chunks (256-thr blocks).
// mode 2: global_load_lds direct (linear dest, inverse-swizzled per-lane src).
// MAP 0: src row = rowoff+r. MAP 1: p=rowoff+r -> (p&3)*H_+(p>>2). MAP 2: p -> (p>>4)*S_+t0+(p&15).
template<int ROWS, int MAP>
__device__ __forceinline__ void stage(const void* base, int mode, int lda, int k0,
                                      int rowoff, int t0, u16* lds, int tid){
  if(mode==2){
    constexpr int NI=(ROWS*8)/256;
    int wv=tid>>6, l=tid&63;
#pragma unroll
    for(int i=0;i<NI;i++){
      int s0=i*256+(wv<<6), s=s0+l;
      int r=s>>3, gc=(s&7)^(r&7);
      int p=rowoff+r, sr;
      if(MAP==0)      sr=p;
      else if(MAP==1) sr=(p&3)*H_+(p>>2);
      else            sr=(p>>4)*S_+t0+(p&15);
      const u16* src=(const u16*)base + (size_t)sr*lda + k0 + gc*8;
      u16* dst=lds + s0*8;             // wave-uniform; HW adds lane*16B
      __builtin_amdgcn_global_load_lds((const __attribute__((address_space(1))) unsigned int*)src,
                                       (__attribute__((address_space(3))) unsigned int*)dst,
                                       16, 0, 0);
    }
  } else {
#pragma unroll
    for(int s0=tid; s0<ROWS*8; s0+=256){
      int r=s0>>3, gc=s0&7, lc=gc^(r&7);
      int p=rowoff+r, sr;
      if(MAP==0)      sr=p;
      else if(MAP==1) sr=(p&3)*H_+(p>>2);
      else            sr=(p>>4)*S_+t0+(p&15);
      f16x8 v=load8_h(base, (size_t)sr*lda + k0 + gc*8, mode);
      *(f16x8*)(lds + r*64 + lc*8)=v;
    }
  }
}

// MFMA 16x16x32 fragment from swizzled LDS tile: lane -> row r0+(l&15), chunk kc+(l>>4), un-XOR.
__device__ __forceinline__ f16x8 frag_ld(const u16* lds, int r0, int kc, int lane){
  int r = r0 + (lane&15);
  int c = (kc + (lane>>4)) ^ (r&7);
  return *(const f16x8*)(lds + r*64 + c*8);
}

// ---- 128x128-tile GEMM: C = A * B^T + biasf. amode/bmode: <0 -> *flag, else literal.
// OUTMODE 0: relu+fp16. 1: fp32. 2: fp16 (no relu).
template<int AMAP, int BMAP, int OUTMODE>
__global__ __launch_bounds__(256,3) void gemm128(const void* A, const void* Bt, void* C,
    const float* __restrict__ biasf, const int* __restrict__ flag,
    int K, int lda, int ldb, int ldc, int t0, int amode, int bmode){
  int m=*flag;
  int am = amode<0 ? m : amode;
  int bm_ = bmode<0 ? m : bmode;
  __shared__ u16 As[128*64];
  __shared__ u16 Bs[128*64];
  int tid=threadIdx.x, lane=tid&63, w=tid>>6;
  int bm=blockIdx.y*128, bn=blockIdx.x*128;
  int wm=(w&1)*64, wn=(w>>1)*64;
  f32x4 acc[4][4];
#pragma unroll
  for(int i=0;i<4;i++)
#pragma unroll
    for(int j=0;j<4;j++) acc[i][j]=(f32x4)(0.f);
  for(int k0=0;k0<K;k0+=64){
    stage<128,AMAP>(A , am,  lda, k0, bm, t0, As, tid);
    stage<128,BMAP>(Bt, bm_, ldb, k0, bn, t0, Bs, tid);
    __syncthreads();
#pragma unroll
    for(int kk=0;kk<2;kk++){
      f16x8 af[4], bq[4];
#pragma unroll
      for(int i=0;i<4;i++) af[i]=frag_ld(As, wm+i*16, kk*4, lane);
#pragma unroll
      for(int j=0;j<4;j++) bq[j]=frag_ld(Bs, wn+j*16, kk*4, lane);
#pragma unroll
      for(int i=0;i<4;i++)
#pragma unroll
        for(int j=0;j<4;j++)
          acc[i][j]=__builtin_amdgcn_mfma_f32_16x16x32_f16(af[i],bq[j],acc[i][j],0,0,0);
    }
    __syncthreads();
  }
  int rl=lane>>4, cl=lane&15;
#pragma unroll
  for(int j=0;j<4;j++){
    int col=bn+wn+j*16+cl;
    float bb=biasf[col];
#pragma unroll
    for(int i=0;i<4;i++){
#pragma unroll
      for(int r=0;r<4;r++){
        int row=bm+wm+i*16+rl*4+r;
        float v=acc[i][j][r]+bb;
        if(OUTMODE==0){ v=fmaxf(v,0.f); ((u16*)C)[(size_t)row*ldc+col]=f2h(v); }
        else if(OUTMODE==2){ ((u16*)C)[(size_t)row*ldc+col]=f2h(v); }
        else { ((float*)C)[(size_t)row*ldc+col]=v; }
      }
    }
  }
}

// ---- persistent chunk-LSTM v7: h stage via NORMAL CACHED loads (L2 reuse within XCD;
// safe: every hh address is read exactly once per launch, writes bypass L2 (sc0sc1),
// and the kernel-start buffer_inv clears prior-launch lines). Split-half stage/MFMA
// overlap hides the second half's L2 latency. Whh pinned in AGPRs.
// Grid 256 (1/CU), 512 threads. grp=blockIdx&7 (bm=grp*32), ci=blockIdx>>3 (bn=ci*128).
__global__ __launch_bounds__(512,2) void lstm_persist(u16* __restrict__ hh,
        const u16* __restrict__ Whhp, const u16* __restrict__ xgp,
        float* __restrict__ cst, int* __restrict__ cntc, int tbase){
  __shared__ u16 As[16*2048];     // 64 KB: 16 k-tiles [32][64], XOR-swizzled
  __shared__ float gs[32*132];    // 16.9 KB, stride 132
  int tid=threadIdx.x, lane=tid&63, w=tid>>6;
  int grp=blockIdx.x&7, ci=blockIdx.x>>3;
  int bm=grp*32, bn=ci*128;
  int* flags = cntc + grp*64;

  // Whh slice -> 32 f16x8 (wave's 16 cols x K=1024), pinned in AGPRs.
  f16x8 bw[32];
#pragma unroll
  for(int t=0;t<32;t++){
    int p = bn + w*16 + (lane&15);
    int k = t*32 + (lane>>4)*8;
    bw[t]=*(const f16x8*)(Whhp + (size_t)p*H_ + k);
  }
#pragma unroll
  for(int t=0;t<32;t++) asm volatile("" : "+a"(bw[t]));

  // cells: 32 rows x 32 units = 1024; thread owns (rl0,u0) and (rl1,u0).
  int rl0=tid>>5, rl1=(tid+512)>>5, u0=tid&31;
  int gu=(bn>>2)+u0;
  float c0=cst[(size_t)(bm+rl0)*H_+gu];
  float c1=cst[(size_t)(bm+rl1)*H_+gu];

  for(int dt=0;dt<CH_;dt++){
    // xg prefetch (fp16, cached) — independent of h, issued BEFORE the barrier
    f16x4 xv0=*(const f16x4*)(xgp + ((size_t)(bm+rl0)*CH_+dt)*G_ + bn + u0*4);
    f16x4 xv1=*(const f16x4*)(xgp + ((size_t)(bm+rl1)*CH_+dt)*G_ + bn + u0*4);
    if(dt) bar_flags32(flags, tbase+dt, ci, lane, w);
    int slotPrev=(dt+CH_-1)&(CH_-1);
    const u16* hbase = hh + (size_t)slotPrev*H_;
    // ---- half 1: stage k-tiles 0-7 (cached loads -> regs -> LDS swizzled)
    {
      u32x4 tmp[4];
#pragma unroll
      for(int i=0;i<4;i++){
        int s=tid+i*512, kt=s>>8, r=(s>>3)&31, gc=s&7;
        tmp[i]=*(const u32x4*)(hbase + (size_t)(bm+r)*(CH_*H_) + kt*64 + gc*8);
      }
#pragma unroll
      for(int i=0;i<4;i++){
        int s=tid+i*512, kt=s>>8, r=(s>>3)&31, gc=s&7, lc=gc^(r&7);
        *(u32x4*)(As + kt*2048 + r*64 + lc*8)=tmp[i];
      }
    }
    __syncthreads();
    // ---- issue half-2 loads; MFMA on half 1 while they fly
    u32x4 tmp2[4];
#pragma unroll
    for(int i=0;i<4;i++){
      int s=tid+(i+4)*512, kt=s>>8, r=(s>>3)&31, gc=s&7;
      tmp2[i]=*(const u32x4*)(hbase + (size_t)(bm+r)*(CH_*H_) + kt*64 + gc*8);
    }
    f32x4 acc0=(f32x4)(0.f), acc1=(f32x4)(0.f);
#pragma unroll
    for(int t=0;t<16;t++){
      int kt=t>>1, kk=t&1;
      f16x8 af0=frag_ld(As+kt*2048, 0,  kk*4, lane);
      f16x8 af1=frag_ld(As+kt*2048, 16, kk*4, lane);
      acc0=__builtin_amdgcn_mfma_f32_16x16x32_f16(af0,bw[t],acc0,0,0,0);
      acc1=__builtin_amdgcn_mfma_f32_16x16x32_f16(af1,bw[t],acc1,0,0,0);
    }
#pragma unroll
    for(int i=0;i<4;i++){
      int s=tid+(i+4)*512, kt=s>>8, r=(s>>3)&31, gc=s&7, lc=gc^(r&7);
      *(u32x4*)(As + kt*2048 + r*64 + lc*8)=tmp2[i];
    }
    __syncthreads();
    // ---- MFMA on half 2
#pragma unroll
    for(int t=16;t<32;t++){
      int kt=t>>1, kk=t&1;
      f16x8 af0=frag_ld(As+kt*2048, 0,  kk*4, lane);
      f16x8 af1=frag_ld(As+kt*2048, 16, kk*4, lane);
      acc0=__builtin_amdgcn_mfma_f32_16x16x32_f16(af0,bw[t],acc0,0,0,0);
      acc1=__builtin_amdgcn_mfma_f32_16x16x32_f16(af1,bw[t],acc1,0,0,0);
    }
    // gates -> gs (single pass); C/D: col=lane&15, row=(lane>>4)*4+r
#pragma unroll
    for(int r=0;r<4;r++){
      gs[(   (lane>>4)*4+r)*132 + w*16+(lane&15)]=acc0[r];
      gs[(16+(lane>>4)*4+r)*132 + w*16+(lane&15)]=acc1[r];
    }
    __syncthreads();
    // elementwise (2 cells/thread); coherent h store
    {
      float4 gv=*(const float4*)&gs[rl0*132+u0*4];
      float ii=1.f/(1.f+__expf(-(gv.x+(float)xv0[0])));
      float ff=1.f/(1.f+__expf(-(gv.y+(float)xv0[1])));
      float gg=1.f-2.f/(__expf(2.f*(gv.z+(float)xv0[2]))+1.f);
      float oo=1.f/(1.f+__expf(-(gv.w+(float)xv0[3])));
      c0=ff*c0+ii*gg;
      float th=1.f-2.f/(__expf(2.f*c0)+1.f);
      store_c2(hh + ((size_t)(bm+rl0)*CH_+dt)*H_ + gu, f2h(oo*th));
    }
    {
      float4 gv=*(const float4*)&gs[rl1*132+u0*4];
      float ii=1.f/(1.f+__expf(-(gv.x+(float)xv1[0])));
      float ff=1.f/(1.f+__expf(-(gv.y+(float)xv1[1])));
      float gg=1.f-2.f/(__expf(2.f*(gv.z+(float)xv1[2]))+1.f);
      float oo=1.f/(1.f+__expf(-(gv.w+(float)xv1[3])));
      c1=ff*c1+ii*gg;
      float th=1.f-2.f/(__expf(2.f*c1)+1.f);
      store_c2(hh + ((size_t)(bm+rl1)*CH_+dt)*H_ + gu, f2h(oo*th));
    }
    // next bar_flags32's __syncthreads orders gs reads vs next step's writes
  }
  cst[(size_t)(bm+rl0)*H_+gu]=c0;
  cst[(size_t)(bm+rl1)*H_+gu]=c1;
}

// ---- fallback per-step LSTM (low-ws tier): gates = xg(fp16) + h_prev @ Whh(perm)^T.
__global__ __launch_bounds__(256,2) void lstm_step(u16* __restrict__ hh, int slotPrev, int dt,
        const void* __restrict__ Whh, const u16* __restrict__ xg,
        float* __restrict__ cst, const int* __restrict__ flag){
  int m=*flag;
  __shared__ u16 As[64*64];
  __shared__ u16 Bs[64*64];
  __shared__ float gs[64*64];
  int tid=threadIdx.x, lane=tid&63, w=tid>>6;
  int bm=blockIdx.y*64, bn=blockIdx.x*64;
  int wm=(w&1)*32, wn=(w>>1)*32;
  f32x4 acc[2][2];
#pragma unroll
  for(int i=0;i<2;i++)
#pragma unroll
    for(int j=0;j<2;j++) acc[i][j]=(f32x4)(0.f);
  for(int k0=0;k0<H_;k0+=64){
    stage<64,0>(hh + slotPrev*H_, 2, CH_*H_, k0, bm, 0, As, tid);
    stage<64,1>(Whh,              m, H_,     k0, bn, 0, Bs, tid);
    __syncthreads();
#pragma unroll
    for(int kk=0;kk<2;kk++){
      f16x8 af[2], bq[2];
#pragma unroll
      for(int i=0;i<2;i++) af[i]=frag_ld(As, wm+i*16, kk*4, lane);
#pragma unroll
      for(int j=0;j<2;j++) bq[j]=frag_ld(Bs, wn+j*16, kk*4, lane);
#pragma unroll
      for(int i=0;i<2;i++)
#pragma unroll
        for(int j=0;j<2;j++)
          acc[i][j]=__builtin_amdgcn_mfma_f32_16x16x32_f16(af[i],bq[j],acc[i][j],0,0,0);
    }
    __syncthreads();
  }
  int rl=lane>>4, cl=lane&15;
#pragma unroll
  for(int j=0;j<2;j++){
    int coll=wn+j*16+cl;
#pragma unroll
    for(int i=0;i<2;i++){
#pragma unroll
      for(int r=0;r<4;r++){
        int rowl=wm+i*16+rl*4+r;
        float xv=(float)((const _Float16*)xg)[((size_t)(bm+rowl)*CH_+dt)*G_ + bn+coll];
        gs[rowl*64+coll]=acc[i][j][r] + xv;
      }
    }
  }
  __syncthreads();
#pragma unroll
  for(int p=0;p<4;p++){
    int idx=p*256+tid;
    int rowl=idx>>4, u=idx&15;
    float4 gv = *(const float4*)&gs[rowl*64+u*4];
    float ii=1.f/(1.f+__expf(-gv.x));
    float ff=1.f/(1.f+__expf(-gv.y));
    float gg=1.f-2.f/(__expf(2.f*gv.z)+1.f);
    float oo=1.f/(1.f+__expf(-gv.w));
    int gb=bm+rowl;
    int gu=(bn>>2)+u;
    size_t ci=(size_t)gb*H_+gu;
    float cn=ff*cst[ci]+ii*gg;
    cst[ci]=cn;
    float th=1.f-2.f/(__expf(2.f*cn)+1.f);
    hh[(size_t)gb*(CH_*H_) + dt*H_ + gu]=f2h(oo*th);
  }
}

// ---- heads for one chunk: wave per row rg=b*CH_+dt; output gw=b*S+t0+dt.
__global__ __launch_bounds__(256,2) void heads_chunk(const u16* __restrict__ hh,
      const void* __restrict__ Wl, const void* __restrict__ Wv,
      const float* __restrict__ blf, const int* __restrict__ acts,
      void* __restrict__ out, const int* __restrict__ flag, int t0){
  int m=*flag;
  int rg = blockIdx.x*4 + (threadIdx.x>>6);
  int lane = threadIdx.x & 63;
  const u16* h = hh + (size_t)rg*H_;               // fp16, written via sc0sc1 -> read coherent
  u32x4 hv0=load_c16(h + lane*16);
  u32x4 hv1=load_c16(h + lane*16 + 8);
  f16x8 h0=__builtin_bit_cast(f16x8,hv0), h1=__builtin_bit_cast(f16x8,hv1);
  float hv[16];
#pragma unroll
  for(int k=0;k<8;k++){ hv[k]=(float)h0[k]; hv[8+k]=(float)h1[k]; }
  float dots[19];
#pragma unroll
  for(int j=0;j<19;j++){
    const void* wrow = (j<18) ? Wl : Wv;
    size_t roff = (j<18) ? (size_t)j*H_ : 0;
    float wv_[16];
    if(m){
      const float* f=(const float*)wrow + roff + lane*16;
      float4 a=*(const float4*)f, b=*(const float4*)(f+4), c=*(const float4*)(f+8), d=*(const float4*)(f+12);
      wv_[0]=a.x;wv_[1]=a.y;wv_[2]=a.z;wv_[3]=a.w; wv_[4]=b.x;wv_[5]=b.y;wv_[6]=b.z;wv_[7]=b.w;
      wv_[8]=c.x;wv_[9]=c.y;wv_[10]=c.z;wv_[11]=c.w; wv_[12]=d.x;wv_[13]=d.y;wv_[14]=d.z;wv_[15]=d.w;
    } else {
      const u16* ub=(const u16*)wrow + roff + lane*16;
      s16x8 w0=*(const s16x8*)ub, w1=*(const s16x8*)(ub+8);
#pragma unroll
      for(int k=0;k<8;k++){ wv_[k]=bf2f((u16)w0[k]); wv_[8+k]=bf2f((u16)w1[k]); }
    }
    float d=0.f;
#pragma unroll
    for(int k=0;k<16;k++) d += hv[k]*wv_[k];
#pragma unroll
    for(int mm=1;mm<64;mm<<=1) d += __shfl_xor(d, mm, 64);
    dots[j]=d;
  }
  float lg[18];
#pragma unroll
  for(int j=0;j<18;j++) lg[j]=dots[j]+blf[j];
  float value=dots[18]+blf[18];
  float mx=lg[0];
#pragma unroll
  for(int j=1;j<18;j++) mx=fmaxf(mx,lg[j]);
  float se=0.f, s1=0.f;
#pragma unroll
  for(int j=0;j<18;j++){ float e=__expf(lg[j]-mx); se+=e; s1+=e*(lg[j]-mx); }
  float lse=__logf(se);
  int b=rg>>4, dt=rg&(CH_-1);
  int gw = b*S_ + t0 + dt;
  int a=acts[gw];
  float la=0.f;
#pragma unroll
  for(int j=0;j<18;j++) la = (j==a) ? lg[j] : la;
  float lp=la-mx-lse;
  float ent=lse - s1/se;
  if(lane==0){
    if(m){
      ((float*)out)[gw]=lp; ((float*)out)[M_+gw]=ent; ((float*)out)[2*M_+gw]=value;
    } else {
      ((u16*)out)[gw]=f2bf(lp); ((u16*)out)[M_+gw]=f2bf(ent); ((u16*)out)[2*M_+gw]=f2bf(value);
    }
  }
}

// ---- dtype detect
__global__ void detect(const u16* __restrict__ obs_w, int* __restrict__ flag){
  __shared__ float red[256];
  float mx=0.f;
  for(int i=threadIdx.x;i<4096;i+=256) mx=fmaxf(mx,fabsf(bf2f(obs_w[i])));
  red[threadIdx.x]=mx; __syncthreads();
  for(int s=128;s>0;s>>=1){
    if(threadIdx.x<s) red[threadIdx.x]=fmaxf(red[threadIdx.x],red[threadIdx.x+s]);
    __syncthreads();
  }
  if(threadIdx.x==0) *flag=(red[0]>1e4f)?1:0;
}

// ---- prep: biases, c state, h seed (fp16, slot CH_-1), zero barrier flags.
__global__ void prep(const void* bih, const void* bhh, const void* b1, const void* bl, const void* bv,
                     const void* cx, const void* hx,
                     float* biasg, float* b1f, float* blf, float* cst, u16* hh,
                     int* cnt, const int* __restrict__ flag){
  int m=*flag;
  size_t i=(size_t)blockIdx.x*256+threadIdx.x;
  if(i<G_){ size_t rm=(i&3)*H_+(i>>2); biasg[i]=ldf(bih,rm,m)+ldf(bhh,rm,m); return; }
  i-=G_;
  if(i<H_){ b1f[i]=ldf(b1,i,m); return; }
  i-=H_;
  if(i<19){ blf[i]=(i<18)?ldf(bl,i,m):ldf(bv,0,m); return; }
  i-=19;
  if(i<512){ cnt[i]=0; return; }
  i-=512;
  if(i<(size_t)B_*H_){ cst[i]=ldf(cx,i,m); return; }
  i-=(size_t)B_*H_;
  if(i<(size_t)B_*H_){
    size_t b=i>>10, k=i&1023;
    hh[b*(CH_*H_) + (CH_-1)*H_ + k]=f2h(ldf(hx,i,m));
  }
}

// ---- weight pre-conversion to fp16 (exact from bf16), gate-permuted for Wih/Whh.
__global__ void convw(const void* W1, const void* Wih, const void* Whh,
                      u16* W1h, u16* Wihp, u16* Whhp, const int* __restrict__ flag){
  int m=*flag;
  size_t i=((size_t)blockIdx.x*256+threadIdx.x)*8;
  const size_t n1=(size_t)H_*F_, n2=(size_t)G_*H_;
  if(i<n1){ *(f16x8*)(W1h+i)=load8_h(W1,i,m); return; }
  i-=n1;
  if(i<n2){ size_t p=i>>10, c=i&1023; size_t sr=(p&3)*H_+(p>>2);
            *(f16x8*)(Wihp+i)=load8_h(Wih, sr*H_+c, m); return; }
  i-=n2;
  if(i<n2){ size_t p=i>>10, c=i&1023; size_t sr=(p&3)*H_+(p>>2);
            *(f16x8*)(Whhp+i)=load8_h(Whh, sr*H_+c, m); return; }
}
__global__ void convobs(const void* obs, u16* obsh, const int* __restrict__ flag){
  int m=*flag;
  size_t i=((size_t)blockIdx.x*256+threadIdx.x)*8;
  if(i<(size_t)M_*F_) *(f16x8*)(obsh+i)=load8_h(obs,i,m);
}

extern "C" void kernel_launch(void* const* d_in, const int* in_sizes, int n_in,
                              void* d_out, int out_size, void* d_ws, size_t ws_size,
                              hipStream_t stream){
  const void* obs=d_in[0];
  const void* hx =d_in[1];
  const void* cx =d_in[2];
  const int* acts=(const int*)d_in[3];
  const void* W1 =d_in[4];
  const void* b1 =d_in[5];
  const void* Wih=d_in[6];
  const void* bih=d_in[7];
  const void* Whh=d_in[8];
  const void* bhh=d_in[9];
  const void* Wv =d_in[10];
  const void* bv =d_in[11];
  const void* Wl =d_in[12];
  const void* bl =d_in[13];

  char* w=(char*)d_ws;
  auto alloc=[&](size_t n){ char* p=w; w+=((n+255)&~(size_t)255); return p; };
  int*   flag =(int*)alloc(4);
  int*   cnt  =(int*)alloc(512*4);                 // 8 groups x 64 flag slots (32 used)
  float* biasg=(float*)alloc((size_t)G_*4);
  float* b1f  =(float*)alloc((size_t)H_*4);
  float* blf  =(float*)alloc(32*4);
  float* cst  =(float*)alloc((size_t)B_*H_*4);     // 1 MB fp32 c
  u16*   hh   =(u16*)alloc((size_t)B_*CH_*H_*2);   // 8 MB fp16 h history [B][16][H]
  u16*   xc   =(u16*)alloc((size_t)CR_*H_*2);      // 8 MB fp16 x chunk
  u16*   xg   =(u16*)alloc((size_t)CR_*G_*2);      // 32 MB fp16 xg chunk
  // tiers
  size_t nW=((size_t)H_*F_ + 2*(size_t)G_*H_)*2 + 768;
  bool pathW = ((size_t)(w-(char*)d_ws) + nW) <= ws_size;
  u16 *W1h=0,*Wihp=0,*Whhp=0;
  if(pathW){ W1h=(u16*)alloc((size_t)H_*F_*2); Wihp=(u16*)alloc((size_t)G_*H_*2); Whhp=(u16*)alloc((size_t)G_*H_*2); }
  size_t nXC=(size_t)M_*H_*2 + 256;
  bool pathXC = pathW && (((size_t)(w-(char*)d_ws) + nXC) <= ws_size);
  u16* xcf=0; if(pathXC) xcf=(u16*)alloc((size_t)M_*H_*2);
  size_t nO=(size_t)M_*F_*2 + 256;
  bool pathO = pathXC && (((size_t)(w-(char*)d_ws) + nO) <= ws_size);
  u16* obsh=0; if(pathO) obsh=(u16*)alloc((size_t)M_*F_*2);

  detect<<<1,256,0,stream>>>((const u16*)obs, flag);
  {
    int total=G_+H_+19+512+B_*H_+B_*H_;
    prep<<<(total+255)/256,256,0,stream>>>(bih,bhh,b1,bl,bv,cx,hx, biasg,b1f,blf,cst,hh,cnt, flag);
  }
  if(pathW){
    size_t n=((size_t)H_*F_+2*(size_t)G_*H_)/8;
    convw<<<(int)((n+255)/256),256,0,stream>>>(W1,Wih,Whh, W1h,Wihp,Whhp, flag);
  }
  if(pathO){
    size_t n=(size_t)M_*F_/8;
    convobs<<<(int)((n+255)/256),256,0,stream>>>(obs, obsh, flag);
  }
  if(pathXC){
    gemm128<0,0,0><<<dim3(H_/128, M_/128),256,0,stream>>>(
        pathO?(const void*)obsh:obs, pathW?(const void*)W1h:W1, xcf, b1f, flag,
        F_, F_, F_, H_, 0, pathO?2:-1, pathW?2:-1);
  }

  for(int c=0;c<S_/CH_;c++){
    int t0=c*CH_;
    if(!pathXC){
      gemm128<2,0,0><<<dim3(H_/128, CR_/128),256,0,stream>>>(
          obs, pathW?(const void*)W1h:W1, xc, b1f, flag, F_, F_, F_, H_, t0, -1, pathW?2:-1);
    }
    if(pathXC)
      gemm128<2,0,2><<<dim3(G_/128, CR_/128),256,0,stream>>>(
          xcf, Wihp, xg, biasg, flag, H_, H_, H_, G_, t0, 2, 2);
    else if(pathW)
      gemm128<0,0,2><<<dim3(G_/128, CR_/128),256,0,stream>>>(
          xc, Wihp, xg, biasg, flag, H_, H_, H_, G_, 0, 2, 2);
    else
      gemm128<0,1,2><<<dim3(G_/128, CR_/128),256,0,stream>>>(
          xc, Wih, xg, biasg, flag, H_, H_, H_, G_, 0, 2, -1);

    if(pathW)
      lstm_persist<<<256,512,0,stream>>>(hh, Whhp, xg, cst, cnt, t0);
    else
      for(int dt=0;dt<CH_;dt++)
        lstm_step<<<dim3(G_/64, B_/64),256,0,stream>>>(hh, (dt+CH_-1)&(CH_-1), dt, Whh, xg, cst, flag);

    heads_chunk<<<dim3(CR_/4),256,0,stream>>>(hh, Wl, Wv, blf, acts, d_out, flag, t0);
  }
}